// Round 1
// baseline (11030.008 us; speedup 1.0000x reference)
//
#include <hip/hip_runtime.h>
#include <math.h>

// ---------------------------------------------------------------------------
// SelfConsistNet fused pipeline, f32 correctness-first baseline.
//   K1: conv3x3 s2 (256->512, 16x16->8x8) + BN + ReLU          -> y1
//   K2: conv3x3 s1 (512->512) + BN  (+ fused 1x1 s2 downsample+BN) + ReLU -> y
//   K3: conv3x3 s1 + BN + ReLU                                  -> z1
//   K4: conv3x3 s1 + BN + residual(y) + ReLU                    -> z
//   K5: global-avg-pool + linear head                           -> prediction
//   K6: 1x1-conv embedding                                      -> emb
//   K7: Gram (emb^T emb / sqrt(E)) + sigmoid                    -> vol
// BN scale is folded into staged weights; BN bias added in epilogue.
// Scratch: vol output region doubles as temp storage for y1/z1 (low half)
// and z (high half); d_ws holds y then emb (33.5 MB needed).
// ---------------------------------------------------------------------------

#define NB    256
#define NCLS  200

__device__ __forceinline__ float sigmoidf_(float v) {
    return 1.0f / (1.0f + __expf(-v));
}

// ---------------------------------------------------------------------------
// K1: 3x3 stride-2 conv, Cin=256 (16x16) -> Cout=512 (8x8), BN+ReLU.
// block = 128 thr = (coq 0..15, row 0..7); grid = (8 co-tiles, 256 batch)
// ---------------------------------------------------------------------------
__global__ __launch_bounds__(128)
void conv1_s2_kernel(const float* __restrict__ in, const float* __restrict__ w,
                     const float* __restrict__ bns, const float* __restrict__ bnb,
                     float* __restrict__ out)
{
    const int b   = blockIdx.y;
    const int co0 = blockIdx.x * 64;
    const int tid = threadIdx.x;
    const int coq = tid >> 3;   // 0..15
    const int row = tid & 7;    // 0..7

    __shared__ float s_in[8 * 360];      // 8 ci planes, 18 rows x stride 20
    __shared__ float s_w[8 * 9 * 68];    // [ci][k][co pad 68]
    __shared__ float s_scale[64];

    if (tid < 64) s_scale[tid] = bns[co0 + tid];
    for (int i = tid; i < 8 * 360; i += 128) s_in[i] = 0.0f;

    float acc[4][8];
    #pragma unroll
    for (int j = 0; j < 4; ++j)
        #pragma unroll
        for (int x = 0; x < 8; ++x) acc[j][x] = 0.0f;

    for (int cc = 0; cc < 32; ++cc) {     // 256 ci / 8
        const int ci0 = cc * 8;
        __syncthreads();
        // stage weights (pre-scaled by BN scale): 64co x 8ci x 9 = 4608
        #pragma unroll
        for (int it = 0; it < 36; ++it) {
            int flat = it * 128 + tid;
            int co = flat / 72, r = flat % 72, ci = r / 9, k = r % 9;
            float v = w[(co0 + co) * 2304 + (ci0 + ci) * 9 + k] * s_scale[co];
            s_w[(ci * 9 + k) * 68 + co] = v;
        }
        // stage input planes: 8ci x 256 px (interior of padded plane)
        #pragma unroll
        for (int it = 0; it < 16; ++it) {
            int flat = it * 128 + tid;
            int ci = flat >> 8, p = flat & 255, y = p >> 4, x = p & 15;
            s_in[ci * 360 + (y + 1) * 20 + (x + 1)] =
                in[((size_t)b * 256 + ci0 + ci) * 256 + p];
        }
        __syncthreads();
        for (int ci = 0; ci < 8; ++ci) {
            #pragma unroll
            for (int dy = 0; dy < 3; ++dy) {
                const float* base = &s_in[ci * 360 + (2 * row + dy) * 20];
                float4 a0 = *(const float4*)(base);
                float4 a1 = *(const float4*)(base + 4);
                float4 a2 = *(const float4*)(base + 8);
                float4 a3 = *(const float4*)(base + 12);
                float r16 = base[16];
                float rr[17] = {a0.x,a0.y,a0.z,a0.w, a1.x,a1.y,a1.z,a1.w,
                                a2.x,a2.y,a2.z,a2.w, a3.x,a3.y,a3.z,a3.w, r16};
                float wv[3][4];
                #pragma unroll
                for (int k = 0; k < 3; ++k)
                    *(float4*)&wv[k][0] =
                        *(const float4*)&s_w[(ci * 9 + dy * 3 + k) * 68 + coq * 4];
                #pragma unroll
                for (int x = 0; x < 8; ++x) {
                    #pragma unroll
                    for (int k = 0; k < 3; ++k) {
                        float iv = rr[2 * x + k];
                        #pragma unroll
                        for (int j = 0; j < 4; ++j)
                            acc[j][x] = fmaf(iv, wv[k][j], acc[j][x]);
                    }
                }
            }
        }
    }
    #pragma unroll
    for (int j = 0; j < 4; ++j) {
        int co = co0 + coq * 4 + j;
        float bb = bnb[co];
        size_t o = ((size_t)b * 512 + co) * 64 + row * 8;
        float v[8];
        #pragma unroll
        for (int x = 0; x < 8; ++x) v[x] = fmaxf(acc[j][x] + bb, 0.0f);
        *(float4*)&out[o]     = make_float4(v[0], v[1], v[2], v[3]);
        *(float4*)&out[o + 4] = make_float4(v[4], v[5], v[6], v[7]);
    }
}

// ---------------------------------------------------------------------------
// 3x3 stride-1 conv on 8x8, Cin=512 -> Cout=512, BN folded; optional fused
// 1x1-s2 downsample (from 16x16 x, Cin=256) into same accumulator; optional
// residual add; ReLU always.
// ---------------------------------------------------------------------------
template<bool DOWN, bool RES>
__global__ __launch_bounds__(128)
void conv3x3_s1_kernel(const float* __restrict__ in,   // [B,512,8,8]
                       const float* __restrict__ w,    // [512,512,3,3]
                       const float* __restrict__ bns, const float* __restrict__ bnb,
                       const float* __restrict__ xin,  // [B,256,16,16] (DOWN)
                       const float* __restrict__ wd,   // [512,256]     (DOWN)
                       const float* __restrict__ dbs, const float* __restrict__ dbb,
                       const float* __restrict__ res,  // [B,512,8,8]   (RES)
                       float* __restrict__ out)
{
    const int b   = blockIdx.y;
    const int co0 = blockIdx.x * 64;
    const int tid = threadIdx.x;
    const int coq = tid >> 3;
    const int row = tid & 7;

    __shared__ float s_in[1024];         // main: 8 planes x (10 rows x stride 12)=960; down: 16x64
    __shared__ float s_w[8 * 9 * 68];    // main: [ci][k][co]; down: [ci][co] (16x68)
    __shared__ float s_scale[64];
    __shared__ float s_scale_d[64];

    if (tid < 64) s_scale[tid] = bns[co0 + tid];
    if (DOWN && tid >= 64) s_scale_d[tid - 64] = dbs[co0 + tid - 64];
    for (int i = tid; i < 960; i += 128) s_in[i] = 0.0f;

    float acc[4][8];
    #pragma unroll
    for (int j = 0; j < 4; ++j)
        #pragma unroll
        for (int x = 0; x < 8; ++x) acc[j][x] = 0.0f;

    for (int cc = 0; cc < 64; ++cc) {    // 512 ci / 8
        const int ci0 = cc * 8;
        __syncthreads();
        #pragma unroll
        for (int it = 0; it < 36; ++it) {
            int flat = it * 128 + tid;
            int co = flat / 72, r = flat % 72, ci = r / 9, k = r % 9;
            float v = w[(size_t)(co0 + co) * 4608 + (ci0 + ci) * 9 + k] * s_scale[co];
            s_w[(ci * 9 + k) * 68 + co] = v;
        }
        #pragma unroll
        for (int it = 0; it < 4; ++it) {
            int flat = it * 128 + tid;
            int ci = flat >> 6, p = flat & 63, y = p >> 3, x = p & 7;
            s_in[ci * 120 + (y + 1) * 12 + (x + 1)] =
                in[((size_t)b * 512 + ci0 + ci) * 64 + p];
        }
        __syncthreads();
        for (int ci = 0; ci < 8; ++ci) {
            #pragma unroll
            for (int dy = 0; dy < 3; ++dy) {
                const float* base = &s_in[ci * 120 + (row + dy) * 12];
                float4 a0 = *(const float4*)(base);
                float4 a1 = *(const float4*)(base + 4);
                float r8 = base[8], r9 = base[9];
                float rr[10] = {a0.x,a0.y,a0.z,a0.w, a1.x,a1.y,a1.z,a1.w, r8, r9};
                float wv[3][4];
                #pragma unroll
                for (int k = 0; k < 3; ++k)
                    *(float4*)&wv[k][0] =
                        *(const float4*)&s_w[(ci * 9 + dy * 3 + k) * 68 + coq * 4];
                #pragma unroll
                for (int x = 0; x < 8; ++x) {
                    #pragma unroll
                    for (int k = 0; k < 3; ++k) {
                        float iv = rr[x + k];
                        #pragma unroll
                        for (int j = 0; j < 4; ++j)
                            acc[j][x] = fmaf(iv, wv[k][j], acc[j][x]);
                    }
                }
            }
        }
    }

    if (DOWN) {
        for (int cc = 0; cc < 16; ++cc) {   // 256 ci / 16
            const int ci0 = cc * 16;
            __syncthreads();
            #pragma unroll
            for (int it = 0; it < 8; ++it) {
                int flat = it * 128 + tid;
                int ci = flat >> 6, p = flat & 63, y = p >> 3, x = p & 7;
                s_in[ci * 64 + p] =
                    xin[((size_t)b * 256 + ci0 + ci) * 256 + y * 32 + x * 2];
            }
            #pragma unroll
            for (int it = 0; it < 8; ++it) {
                int flat = it * 128 + tid;
                int co = flat >> 4, ci = flat & 15;
                s_w[ci * 68 + co] = wd[(size_t)(co0 + co) * 256 + ci0 + ci] * s_scale_d[co];
            }
            __syncthreads();
            #pragma unroll
            for (int ci = 0; ci < 16; ++ci) {
                float4 i0 = *(const float4*)&s_in[ci * 64 + row * 8];
                float4 i1 = *(const float4*)&s_in[ci * 64 + row * 8 + 4];
                float4 wq = *(const float4*)&s_w[ci * 68 + coq * 4];
                float xv[8] = {i0.x,i0.y,i0.z,i0.w, i1.x,i1.y,i1.z,i1.w};
                float wj[4] = {wq.x,wq.y,wq.z,wq.w};
                #pragma unroll
                for (int x = 0; x < 8; ++x)
                    #pragma unroll
                    for (int j = 0; j < 4; ++j)
                        acc[j][x] = fmaf(xv[x], wj[j], acc[j][x]);
            }
        }
    }

    #pragma unroll
    for (int j = 0; j < 4; ++j) {
        int co = co0 + coq * 4 + j;
        float bb = bnb[co];
        if (DOWN) bb += dbb[co];
        size_t o = ((size_t)b * 512 + co) * 64 + row * 8;
        float v[8];
        #pragma unroll
        for (int x = 0; x < 8; ++x) v[x] = acc[j][x] + bb;
        if (RES) {
            float4 r0 = *(const float4*)&res[o];
            float4 r1 = *(const float4*)&res[o + 4];
            v[0] += r0.x; v[1] += r0.y; v[2] += r0.z; v[3] += r0.w;
            v[4] += r1.x; v[5] += r1.y; v[6] += r1.z; v[7] += r1.w;
        }
        #pragma unroll
        for (int x = 0; x < 8; ++x) v[x] = fmaxf(v[x], 0.0f);
        *(float4*)&out[o]     = make_float4(v[0], v[1], v[2], v[3]);
        *(float4*)&out[o + 4] = make_float4(v[4], v[5], v[6], v[7]);
    }
}

// ---------------------------------------------------------------------------
// K5: global average pool (8x8) + linear head (512 -> 200), one block per batch
// ---------------------------------------------------------------------------
__global__ __launch_bounds__(256)
void head_kernel(const float* __restrict__ z, const float* __restrict__ hw,
                 float* __restrict__ pred)
{
    const int b = blockIdx.x;
    const int tid = threadIdx.x;
    __shared__ float feat[512];
    for (int c = tid; c < 512; c += 256) {
        const float4* p = (const float4*)&z[((size_t)b * 512 + c) * 64];
        float s = 0.0f;
        #pragma unroll
        for (int i = 0; i < 16; ++i) { float4 v = p[i]; s += v.x + v.y + v.z + v.w; }
        feat[c] = s * (1.0f / 64.0f);
    }
    __syncthreads();
    if (tid < NCLS) {
        float acc = 0.0f;
        const float4* hp = (const float4*)&hw[(size_t)tid * 512];
        #pragma unroll 8
        for (int i = 0; i < 128; ++i) {
            float4 h = hp[i];
            float4 f = *(const float4*)&feat[i * 4];
            acc += h.x * f.x + h.y * f.y + h.z * f.z + h.w * f.w;
        }
        pred[b * NCLS + tid] = acc;
    }
}

// ---------------------------------------------------------------------------
// K6: embedding  emb[b,e,p] = sum_c x[b,c,p]*ew[e,c] + eb[e]
// block: 256 thr = (te 0..31, tp 0..7); tile = 128e x 64p; grid (4, 256)
// ---------------------------------------------------------------------------
__global__ __launch_bounds__(256)
void embed_kernel(const float* __restrict__ x, const float* __restrict__ ew,
                  const float* __restrict__ eb, float* __restrict__ emb)
{
    const int b  = blockIdx.y;
    const int p0 = blockIdx.x * 64;
    const int tid = threadIdx.x;
    const int te = tid >> 3;   // 0..31 (e-quad)
    const int tp = tid & 7;    // 0..7  (p-oct)

    __shared__ float sx[16 * 64];
    __shared__ float sw[16 * 132];

    float acc[4][8];
    #pragma unroll
    for (int j = 0; j < 4; ++j)
        #pragma unroll
        for (int i = 0; i < 8; ++i) acc[j][i] = 0.0f;

    for (int cc = 0; cc < 16; ++cc) {   // 256 c / 16
        const int ci0 = cc * 16;
        __syncthreads();
        #pragma unroll
        for (int it = 0; it < 4; ++it) {
            int flat = it * 256 + tid;
            int ci = flat >> 6, p = flat & 63;
            sx[ci * 64 + p] = x[((size_t)b * 256 + ci0 + ci) * 256 + p0 + p];
        }
        #pragma unroll
        for (int it = 0; it < 8; ++it) {
            int flat = it * 256 + tid;
            int e = flat >> 4, ci = flat & 15;
            sw[ci * 132 + e] = ew[(size_t)e * 256 + ci0 + ci];
        }
        __syncthreads();
        #pragma unroll
        for (int ci = 0; ci < 16; ++ci) {
            float4 x0 = *(const float4*)&sx[ci * 64 + tp * 8];
            float4 x1 = *(const float4*)&sx[ci * 64 + tp * 8 + 4];
            float4 wq = *(const float4*)&sw[ci * 132 + te * 4];
            float xv[8] = {x0.x,x0.y,x0.z,x0.w, x1.x,x1.y,x1.z,x1.w};
            float wj[4] = {wq.x,wq.y,wq.z,wq.w};
            #pragma unroll
            for (int j = 0; j < 4; ++j)
                #pragma unroll
                for (int i = 0; i < 8; ++i)
                    acc[j][i] = fmaf(wj[j], xv[i], acc[j][i]);
        }
    }
    #pragma unroll
    for (int j = 0; j < 4; ++j) {
        int e = te * 4 + j;
        float bb = eb[e];
        size_t o = ((size_t)b * 128 + e) * 256 + p0 + tp * 8;
        float v[8];
        #pragma unroll
        for (int i = 0; i < 8; ++i) v[i] = acc[j][i] + bb;
        *(float4*)&emb[o]     = make_float4(v[0], v[1], v[2], v[3]);
        *(float4*)&emb[o + 4] = make_float4(v[4], v[5], v[6], v[7]);
    }
}

// ---------------------------------------------------------------------------
// K7: Gram + sigmoid: vol[b,q,i] = sigmoid(sum_e emb[b,e,i]*emb[b,e,q]/sqrt(E))
// block: 256 thr = (tq 0..7, ti 0..31); tile = 64q x 256i; grid (4, 256)
// ---------------------------------------------------------------------------
__global__ __launch_bounds__(256)
void gram_kernel(const float* __restrict__ emb, float* __restrict__ vol)
{
    const int b  = blockIdx.y;
    const int q0 = blockIdx.x * 64;
    const int tid = threadIdx.x;
    const int tq = tid >> 5;   // 0..7
    const int ti = tid & 31;   // 0..31

    __shared__ float sq[16 * 64];
    __shared__ float si[16 * 256];

    float acc[8][8];
    #pragma unroll
    for (int q = 0; q < 8; ++q)
        #pragma unroll
        for (int i = 0; i < 8; ++i) acc[q][i] = 0.0f;

    for (int ec = 0; ec < 8; ++ec) {    // 128 e / 16
        const int e0 = ec * 16;
        __syncthreads();
        #pragma unroll
        for (int it = 0; it < 4; ++it) {
            int flat = it * 256 + tid;
            int e = flat >> 6, qq = flat & 63;
            sq[e * 64 + qq] = emb[((size_t)b * 128 + e0 + e) * 256 + q0 + qq];
        }
        #pragma unroll
        for (int it = 0; it < 16; ++it) {
            int flat = it * 256 + tid;
            int e = flat >> 8, ii = flat & 255;
            si[e * 256 + ii] = emb[((size_t)b * 128 + e0 + e) * 256 + ii];
        }
        __syncthreads();
        #pragma unroll
        for (int e = 0; e < 16; ++e) {
            float4 qa = *(const float4*)&sq[e * 64 + tq * 8];
            float4 qb = *(const float4*)&sq[e * 64 + tq * 8 + 4];
            float4 ia = *(const float4*)&si[e * 256 + ti * 4];
            float4 ib = *(const float4*)&si[e * 256 + 128 + ti * 4];
            float qv[8] = {qa.x,qa.y,qa.z,qa.w, qb.x,qb.y,qb.z,qb.w};
            float iv[8] = {ia.x,ia.y,ia.z,ia.w, ib.x,ib.y,ib.z,ib.w};
            #pragma unroll
            for (int q = 0; q < 8; ++q)
                #pragma unroll
                for (int i = 0; i < 8; ++i)
                    acc[q][i] = fmaf(qv[q], iv[i], acc[q][i]);
        }
    }
    const float sc = 0.08838834764831845f;  // 1/sqrt(128)
    #pragma unroll
    for (int q = 0; q < 8; ++q) {
        int qg = q0 + tq * 8 + q;
        size_t o = ((size_t)b * 256 + qg) * 256;
        float4 o0, o1;
        o0.x = sigmoidf_(acc[q][0] * sc); o0.y = sigmoidf_(acc[q][1] * sc);
        o0.z = sigmoidf_(acc[q][2] * sc); o0.w = sigmoidf_(acc[q][3] * sc);
        o1.x = sigmoidf_(acc[q][4] * sc); o1.y = sigmoidf_(acc[q][5] * sc);
        o1.z = sigmoidf_(acc[q][6] * sc); o1.w = sigmoidf_(acc[q][7] * sc);
        *(float4*)&vol[o + ti * 4]       = o0;
        *(float4*)&vol[o + 128 + ti * 4] = o1;
    }
}

// ---------------------------------------------------------------------------
extern "C" void kernel_launch(void* const* d_in, const int* in_sizes, int n_in,
                              void* d_out, int out_size, void* d_ws, size_t ws_size,
                              hipStream_t stream)
{
    const float* x    = (const float*)d_in[0];
    const float* ew   = (const float*)d_in[1];
    const float* eb   = (const float*)d_in[2];
    const float* w1   = (const float*)d_in[3];
    const float* bn1s = (const float*)d_in[4];
    const float* bn1b = (const float*)d_in[5];
    const float* w2   = (const float*)d_in[6];
    const float* bn2s = (const float*)d_in[7];
    const float* bn2b = (const float*)d_in[8];
    const float* wd   = (const float*)d_in[9];
    const float* bnds = (const float*)d_in[10];
    const float* bndb = (const float*)d_in[11];
    const float* w3   = (const float*)d_in[12];
    const float* bn3s = (const float*)d_in[13];
    const float* bn3b = (const float*)d_in[14];
    const float* w4   = (const float*)d_in[15];
    const float* bn4s = (const float*)d_in[16];
    const float* bn4b = (const float*)d_in[17];
    const float* hw   = (const float*)d_in[18];

    float* pred = (float*)d_out;            // [256,200]
    float* vol  = pred + 51200;             // [256,256,256] = 16,777,216 floats
    // scratch choreography (all dead before their space is overwritten):
    float* y1 = vol;                        // K1 out, dead after K2
    float* z1 = vol;                        // K3 out (y1 dead), dead after K4
    float* z  = vol + 8388608;              // K4 out, dead after K5(head)
    float* y  = (float*)d_ws;               // K2 out, dead after K4
    float* emb = (float*)d_ws;              // K6 out (y dead), read by K7

    dim3 cgrid(8, NB);
    conv1_s2_kernel<<<cgrid, 128, 0, stream>>>(x, w1, bn1s, bn1b, y1);
    conv3x3_s1_kernel<true,  false><<<cgrid, 128, 0, stream>>>(
        y1, w2, bn2s, bn2b, x, wd, bnds, bndb, nullptr, y);
    conv3x3_s1_kernel<false, false><<<cgrid, 128, 0, stream>>>(
        y, w3, bn3s, bn3b, nullptr, nullptr, nullptr, nullptr, nullptr, z1);
    conv3x3_s1_kernel<false, true ><<<cgrid, 128, 0, stream>>>(
        z1, w4, bn4s, bn4b, nullptr, nullptr, nullptr, nullptr, y, z);
    head_kernel<<<dim3(NB), 256, 0, stream>>>(z, hw, pred);
    embed_kernel<<<dim3(4, NB), 256, 0, stream>>>(x, ew, eb, emb);
    gram_kernel<<<dim3(4, NB), 256, 0, stream>>>(emb, vol);
}

// Round 2
// 545.349 us; speedup vs baseline: 20.2256x; 20.2256x over previous
//
#include <hip/hip_runtime.h>

// ---------------------------------------------------------------------------
// SelfConsistNet, bf16 MFMA implicit-GEMM pipeline (NHWC activations).
//   prep : fold BN scale into weights, emit bf16 [dydx][cc][co][40] tiles
//   K1   : conv3x3 s2 (256->512) + BN + ReLU            -> y1  (NHWC bf16)
//   K2   : conv3x3 s1 + BN + fused 1x1 s2 downsample+BN + ReLU -> y
//   K3   : conv3x3 s1 + BN + ReLU                       -> z1
//   K4   : conv3x3 s1 + BN + residual(y) + ReLU         -> z
//   head : GAP + linear                                  -> pred
//   gram : fused 1x1 embed (LDS-resident emb) + Gram + sigmoid -> vol
// MFMA: 16x16x32 bf16. A=[M=co][K=ci] (k-contig), B=[K=ci][N=px] read from
// NHWC/px-padded LDS (k-contig per px), C: col=lane&15 (px), row=(l>>4)*4+r (co).
// Scratch: vol region (67.1MB) holds y1|y|z1|z (4 x 16.78MB, exact fit);
// d_ws holds only prepped weights (21.0MB < 33.5MB proven-safe).
// ---------------------------------------------------------------------------

using short8 = __attribute__((ext_vector_type(8))) short;   // 8 bf16 (4 VGPR)
using f32x4  = __attribute__((ext_vector_type(4))) float;   // MFMA acc
typedef unsigned short u16;
typedef unsigned int   u32;

#define MFMA(a,b,c) __builtin_amdgcn_mfma_f32_16x16x32_bf16((a),(b),(c),0,0,0)

__device__ __forceinline__ u16 f2b(float f){
    u32 u = __builtin_bit_cast(u32, f);
    u += 0x7FFFu + ((u >> 16) & 1u);        // RNE
    return (u16)(u >> 16);
}
__device__ __forceinline__ float b2f(u16 h){
    u32 u = ((u32)h) << 16;
    return __builtin_bit_cast(float, u);
}
__device__ __forceinline__ u32 pack2(float a, float b){
    return (u32)f2b(a) | ((u32)f2b(b) << 16);
}
__device__ __forceinline__ float sigmoidf_(float v){
    return 1.0f / (1.0f + __expf(-v));
}

// ---------------------------------------------------------------------------
// Weight prep: one thread per output element.
//   conv3x3: wp[((dydx*NCC+cc)*512+co)*40 + j] = w[co][cc*32+j][dydx]*s[co], j<32
//   1x1   :  wp[(cc*CO+e)*40 + j]              = w[e][cc*32+j]*(s?s:1)
// Pad j=32..39 zero. Totals: wp2/3/4 2,949,120 ea; wp1 1,474,560; wpd 163,840;
// wpe 40,960  => 10,526,720 elems = 41120*256 threads exactly.
// ---------------------------------------------------------------------------
__global__ __launch_bounds__(256)
void prep_kernel(const float* __restrict__ w1, const float* __restrict__ s1,
                 const float* __restrict__ w2, const float* __restrict__ s2,
                 const float* __restrict__ w3, const float* __restrict__ s3,
                 const float* __restrict__ w4, const float* __restrict__ s4,
                 const float* __restrict__ wd, const float* __restrict__ sd,
                 const float* __restrict__ ew,
                 u16* __restrict__ wp1, u16* __restrict__ wp2,
                 u16* __restrict__ wp3, u16* __restrict__ wp4,
                 u16* __restrict__ wpd, u16* __restrict__ wpe)
{
    const int N2 = 9*16*512*40, N1 = 9*8*512*40, ND = 8*512*40, NE = 8*128*40;
    int t = blockIdx.x * 256 + threadIdx.x;
    if (t < N2) {                     // wp2
        int j = t % 40; int r = t / 40; int co = r & 511; int q = r >> 9;
        int cc = q & 15; int dydx = q >> 4;
        float v = (j < 32) ? w2[(co*512 + cc*32 + j)*9 + dydx] * s2[co] : 0.f;
        wp2[t] = f2b(v); return;
    }
    t -= N2;
    if (t < N2) {                     // wp3
        int j = t % 40; int r = t / 40; int co = r & 511; int q = r >> 9;
        int cc = q & 15; int dydx = q >> 4;
        float v = (j < 32) ? w3[(co*512 + cc*32 + j)*9 + dydx] * s3[co] : 0.f;
        wp3[t] = f2b(v); return;
    }
    t -= N2;
    if (t < N2) {                     // wp4
        int j = t % 40; int r = t / 40; int co = r & 511; int q = r >> 9;
        int cc = q & 15; int dydx = q >> 4;
        float v = (j < 32) ? w4[(co*512 + cc*32 + j)*9 + dydx] * s4[co] : 0.f;
        wp4[t] = f2b(v); return;
    }
    t -= N2;
    if (t < N1) {                     // wp1 (CI=256 -> 8 cc)
        int j = t % 40; int r = t / 40; int co = r & 511; int q = r >> 9;
        int cc = q & 7; int dydx = q >> 3;
        float v = (j < 32) ? w1[(co*256 + cc*32 + j)*9 + dydx] * s1[co] : 0.f;
        wp1[t] = f2b(v); return;
    }
    t -= N1;
    if (t < ND) {                     // wpd (1x1, 512x256)
        int j = t % 40; int r = t / 40; int co = r & 511; int cc = r >> 9;
        float v = (j < 32) ? wd[co*256 + cc*32 + j] * sd[co] : 0.f;
        wpd[t] = f2b(v); return;
    }
    t -= ND;
    if (t < NE) {                     // wpe (1x1, 128x256, no BN)
        int j = t % 40; int r = t / 40; int e = r & 127; int cc = r >> 7;
        float v = (j < 32) ? ew[e*256 + cc*32 + j] : 0.f;
        wpe[t] = f2b(v);
    }
}

// ---------------------------------------------------------------------------
// K1: conv3x3 stride2, x NCHW f32 [256,256,16,16] -> y1 NHWC bf16 [256,64px,512]
// block 512thr = 8 waves (wco 0..3 x bb 0..1); BM=256co, BN=128px(2 batches).
// grid (2 co-tiles, 128 batch-pairs). LDS: act [2][2][289][40] (17x17 padded
// transposed planes), w [2][256][40]. 72 steps = 8cc x 9dydx, 1 barrier/step.
// ---------------------------------------------------------------------------
__global__ __launch_bounds__(512, 2)
void conv1_kernel(const float* __restrict__ x, const u16* __restrict__ wp,
                  const float* __restrict__ bnb, u16* __restrict__ out)
{
    const int cot = blockIdx.x;          // 0..1
    const int b0  = blockIdx.y * 2;
    const int tid = threadIdx.x;
    const int wid = tid >> 6, lane = tid & 63;
    const int ln = lane & 15, kg = lane >> 4;
    const int wco = wid >> 1;            // 0..3 (co quarter)
    const int bb  = wid & 1;             // 0..1 (batch)

    __shared__ u16 actb[2][2*289*40];    // 92,480 B
    __shared__ u16 wb[2][256*40];        // 40,960 B

    { // zero act bufs (halo rows must be 0)
        short8 zz = {0,0,0,0,0,0,0,0};
        short8* ab = (short8*)&actb[0][0];
        for (int j = tid; j < 2*2*289*40/8; j += 512) ab[j] = zz;
    }
    __syncthreads();

    auto stage_act = [&](int cc, int p){
        #pragma unroll
        for (int it = 0; it < 16; ++it){
            int f = it*512 + tid;                    // 8192 dwords
            int bb2 = f >> 12; int rem = f & 4095;
            int cip = rem >> 8; int px = rem & 255;
            const float* src = &x[(((size_t)(b0+bb2)*256 + cc*32 + 2*cip)*256) + px];
            float v0 = src[0], v1 = src[256];
            int r = ((px >> 4) + 1)*17 + (px & 15) + 1;
            *(u32*)&actb[p][(bb2*289 + r)*40 + 2*cip] = pack2(v0, v1);
        }
    };
    auto stage_w = [&](int cc, int dydx, int p){
        int gbase = ((dydx*8 + cc)*512 + cot*256)*40;
        #pragma unroll
        for (int it = 0; it < 3; ++it){
            int j = it*512 + tid;
            if (j < 1280)
                *(short8*)&wb[p][j*8] = *(const short8*)&wp[gbase + j*8];
        }
    };

    stage_act(0, 0);
    stage_w(0, 0, 0);
    __syncthreads();

    f32x4 zero4 = {0.f,0.f,0.f,0.f};
    f32x4 acc[4][4];
    #pragma unroll
    for (int mf = 0; mf < 4; ++mf)
        #pragma unroll
        for (int nf = 0; nf < 4; ++nf) acc[mf][nf] = zero4;

    int bbase[4];
    #pragma unroll
    for (int nf = 0; nf < 4; ++nf){
        int px = nf*16 + ln;
        bbase[nf] = (bb*289 + 34*(px>>3) + 2*(px&7))*40 + kg*8;
    }

    int s = 0;
    for (int cc = 0; cc < 8; ++cc){
        for (int d = 0; d < 9; ++d){
            int ns = s + 1;
            if (ns < 72) stage_w(ns/9, ns%9, ns & 1);
            if (d == 8 && cc < 7) stage_act(cc+1, (cc+1) & 1);
            const u16* wbp = wb[s & 1];
            const u16* abp = actb[cc & 1];
            int dy = d/3, dx = d - dy*3;
            int shift = (dy*17 + dx)*40;
            short8 A[4];
            #pragma unroll
            for (int mf = 0; mf < 4; ++mf)
                A[mf] = *(const short8*)&wbp[(wco*64 + mf*16 + ln)*40 + kg*8];
            #pragma unroll
            for (int nf = 0; nf < 4; ++nf){
                short8 B = *(const short8*)&abp[bbase[nf] + shift];
                #pragma unroll
                for (int mf = 0; mf < 4; ++mf)
                    acc[mf][nf] = MFMA(A[mf], B, acc[mf][nf]);
            }
            __syncthreads();
            ++s;
        }
    }

    #pragma unroll
    for (int mf = 0; mf < 4; ++mf){
        int co0 = cot*256 + wco*64 + mf*16 + kg*4;
        float4 bv = *(const float4*)&bnb[co0];
        #pragma unroll
        for (int nf = 0; nf < 4; ++nf){
            int px = nf*16 + ln;
            size_t o = (((size_t)(b0+bb)*64) + px)*512 + co0;
            f32x4 a = acc[mf][nf];
            ushort4 st;
            st.x = f2b(fmaxf(a[0] + bv.x, 0.f));
            st.y = f2b(fmaxf(a[1] + bv.y, 0.f));
            st.z = f2b(fmaxf(a[2] + bv.z, 0.f));
            st.w = f2b(fmaxf(a[3] + bv.w, 0.f));
            *(ushort4*)&out[o] = st;
        }
    }
}

// ---------------------------------------------------------------------------
// K2/K3/K4: conv3x3 s1 on 8x8 NHWC bf16, Cin=Cout=512, BN folded; optional
// fused 1x1-s2 downsample from x (NCHW f32, Cin=256); optional residual; ReLU.
// block 512thr = 8 waves (wco 0..1 x bb 0..3); BM=128co, BN=256px(4 batches).
// grid (4, 64). LDS: act [2][4][100][40] 10x10-padded, w [2][3][128][40].
// 48 steps = 16cc x 3dy (3 dx per step), 1 barrier/step.
// ---------------------------------------------------------------------------
template<int DOWN, int RES>
__global__ __launch_bounds__(512, 2)
void conv_s1_kernel(const u16* __restrict__ in, const u16* __restrict__ wp,
                    const float* __restrict__ bnb,
                    const float* __restrict__ x, const u16* __restrict__ wpd,
                    const float* __restrict__ dbb,
                    const u16* __restrict__ res, u16* __restrict__ out)
{
    const int cot = blockIdx.x;          // 0..3
    const int b0  = blockIdx.y * 4;
    const int tid = threadIdx.x;
    const int wid = tid >> 6, lane = tid & 63;
    const int ln = lane & 15, kg = lane >> 4;
    const int wco = wid >> 2;            // 0..1
    const int bb  = wid & 3;             // 0..3

    __shared__ u16 actb[2][4*100*40];    // 64,000 B
    __shared__ u16 wb[2][3*128*40];      // 61,440 B

    {
        short8 zz = {0,0,0,0,0,0,0,0};
        short8* ab = (short8*)&actb[0][0];
        for (int j = tid; j < 2*4*100*40/8; j += 512) ab[j] = zz;
    }
    __syncthreads();

    auto stage_act = [&](int cc, int p){
        #pragma unroll
        for (int it = 0; it < 2; ++it){
            int j = it*512 + tid;                    // 1024 b128
            int bb2 = j >> 8; int rem = j & 255;
            int px = rem >> 2, cig = rem & 3;
            int rr = ((px>>3)+1)*10 + (px&7) + 1;
            *(short8*)&actb[p][(bb2*100 + rr)*40 + cig*8] =
                *(const short8*)&in[(((size_t)(b0+bb2)*64 + px)*512) + cc*32 + cig*8];
        }
    };
    auto stage_w = [&](int cc, int dy, int p){
        #pragma unroll
        for (int it = 0; it < 4; ++it){
            int j = it*512 + tid;
            if (j < 1920){
                int dx = j / 640, jj = j - dx*640;
                int g = (((dy*3 + dx)*16 + cc)*512 + cot*128)*40 + jj*8;
                *(short8*)&wb[p][dx*5120 + jj*8] = *(const short8*)&wp[g];
            }
        }
    };

    stage_act(0, 0);
    stage_w(0, 0, 0);
    __syncthreads();

    f32x4 zero4 = {0.f,0.f,0.f,0.f};
    f32x4 acc[4][4];
    #pragma unroll
    for (int mf = 0; mf < 4; ++mf)
        #pragma unroll
        for (int nf = 0; nf < 4; ++nf) acc[mf][nf] = zero4;

    int bbase[4];
    #pragma unroll
    for (int nf = 0; nf < 4; ++nf){
        int px = nf*16 + ln;
        bbase[nf] = (bb*100 + (px>>3)*10 + (px&7))*40 + kg*8;
    }

    int s = 0;
    for (int cc = 0; cc < 16; ++cc){
        for (int dy = 0; dy < 3; ++dy){
            int ns = s + 1;
            if (ns < 48) stage_w(ns/3, ns%3, ns & 1);
            if (dy == 2 && cc < 15) stage_act(cc+1, (cc+1) & 1);
            const u16* wbp = wb[s & 1];
            const u16* abp = actb[cc & 1];
            #pragma unroll
            for (int dx = 0; dx < 3; ++dx){
                int shift = (dy*10 + dx)*40;
                short8 A[4];
                #pragma unroll
                for (int mf = 0; mf < 4; ++mf)
                    A[mf] = *(const short8*)&wbp[dx*5120 + (wco*64 + mf*16 + ln)*40 + kg*8];
                #pragma unroll
                for (int nf = 0; nf < 4; ++nf){
                    short8 B = *(const short8*)&abp[bbase[nf] + shift];
                    #pragma unroll
                    for (int mf = 0; mf < 4; ++mf)
                        acc[mf][nf] = MFMA(A[mf], B, acc[mf][nf]);
                }
            }
            __syncthreads();
            ++s;
        }
    }

    if (DOWN){
        // fused 1x1 stride-2 downsample from x (NCHW f32), K=256 in 8 chunks
        for (int dc = 0; dc < 8; ++dc){
            #pragma unroll
            for (int it = 0; it < 8; ++it){
                int f = it*512 + tid;                // 4096 dwords
                int bb2 = f >> 10; int rem = f & 1023;
                int cip = rem >> 6, px = rem & 63;
                int ipx = (px>>3)*32 + (px&7)*2;
                const float* src = &x[(((size_t)(b0+bb2)*256 + dc*32 + 2*cip)*256) + ipx];
                *(u32*)&actb[0][(bb2*64 + px)*40 + 2*cip] = pack2(src[0], src[256]);
            }
            for (int j = tid; j < 640; j += 512)
                *(short8*)&wb[0][j*8] = *(const short8*)&wpd[(dc*512 + cot*128)*40 + j*8];
            __syncthreads();
            short8 A[4];
            #pragma unroll
            for (int mf = 0; mf < 4; ++mf)
                A[mf] = *(const short8*)&wb[0][(wco*64 + mf*16 + ln)*40 + kg*8];
            #pragma unroll
            for (int nf = 0; nf < 4; ++nf){
                short8 B = *(const short8*)&actb[0][(bb*64 + nf*16 + ln)*40 + kg*8];
                #pragma unroll
                for (int mf = 0; mf < 4; ++mf)
                    acc[mf][nf] = MFMA(A[mf], B, acc[mf][nf]);
            }
            __syncthreads();
        }
    }

    #pragma unroll
    for (int mf = 0; mf < 4; ++mf){
        int co0 = cot*128 + wco*64 + mf*16 + kg*4;
        float4 bv = *(const float4*)&bnb[co0];
        if (DOWN){
            float4 dv = *(const float4*)&dbb[co0];
            bv.x += dv.x; bv.y += dv.y; bv.z += dv.z; bv.w += dv.w;
        }
        #pragma unroll
        for (int nf = 0; nf < 4; ++nf){
            int px = nf*16 + ln;
            size_t o = (((size_t)(b0+bb)*64) + px)*512 + co0;
            f32x4 a = acc[mf][nf];
            float v0 = a[0] + bv.x, v1 = a[1] + bv.y;
            float v2 = a[2] + bv.z, v3 = a[3] + bv.w;
            if (RES){
                ushort4 rv = *(const ushort4*)&res[o];
                v0 += b2f(rv.x); v1 += b2f(rv.y); v2 += b2f(rv.z); v3 += b2f(rv.w);
            }
            ushort4 st;
            st.x = f2b(fmaxf(v0, 0.f)); st.y = f2b(fmaxf(v1, 0.f));
            st.z = f2b(fmaxf(v2, 0.f)); st.w = f2b(fmaxf(v3, 0.f));
            *(ushort4*)&out[o] = st;
        }
    }
}

// ---------------------------------------------------------------------------
// head: GAP(8x8) + linear 512->200. z NHWC bf16. One block per batch.
// ---------------------------------------------------------------------------
__global__ __launch_bounds__(256)
void head_kernel(const u16* __restrict__ z, const float* __restrict__ hw,
                 float* __restrict__ pred)
{
    const int b = blockIdx.x, tid = threadIdx.x;
    __shared__ float feat[512];
    float s0 = 0.f, s1 = 0.f;
    for (int px = 0; px < 64; ++px){
        u32 u = *(const u32*)&z[(((size_t)b*64 + px)*512) + 2*tid];
        s0 += b2f((u16)(u & 0xFFFF));
        s1 += b2f((u16)(u >> 16));
    }
    feat[2*tid]   = s0 * (1.f/64.f);
    feat[2*tid+1] = s1 * (1.f/64.f);
    __syncthreads();
    if (tid < 200){
        float acc = 0.f;
        const float4* hp = (const float4*)&hw[(size_t)tid*512];
        #pragma unroll 8
        for (int i = 0; i < 128; ++i){
            float4 h = hp[i];
            float4 f = *(const float4*)&feat[i*4];
            acc += h.x*f.x + h.y*f.y + h.z*f.z + h.w*f.w;
        }
        pred[b*200 + tid] = acc;
    }
}

// ---------------------------------------------------------------------------
// gram: fused embed (emb LDS-resident, [256px][136e] bf16) + Gram + sigmoid.
// One block (512thr, 8 waves) per batch.
// Phase A: emb = x(1x1 conv, K=256) + bias; wave w owns px [w*32, w*32+32).
// Phase B: vol[q][i] = sigmoid(emb_row(q) . emb_row(i) / sqrt(128)).
// ---------------------------------------------------------------------------
__global__ __launch_bounds__(512, 2)
void gram_kernel(const float* __restrict__ x, const u16* __restrict__ wpe,
                 const float* __restrict__ eb, float* __restrict__ vol)
{
    const int b = blockIdx.x, tid = threadIdx.x;
    const int wid = tid >> 6, lane = tid & 63;
    const int ln = lane & 15, kg = lane >> 4;

    __shared__ u16 embl[256*136];        // 69,632 B
    __shared__ u16 xbl[256*40];          // 20,480 B
    __shared__ u16 ewl[128*40];          // 10,240 B

    f32x4 zero4 = {0.f,0.f,0.f,0.f};
    f32x4 ae[8][2];
    #pragma unroll
    for (int mf = 0; mf < 8; ++mf){ ae[mf][0] = zero4; ae[mf][1] = zero4; }

    for (int cc = 0; cc < 8; ++cc){
        __syncthreads();
        #pragma unroll
        for (int it = 0; it < 8; ++it){
            int f = it*512 + tid;                // 4096 dwords
            int cip = f >> 8, px = f & 255;
            const float* src = &x[(((size_t)b*256 + cc*32 + 2*cip)*256) + px];
            *(u32*)&xbl[px*40 + 2*cip] = pack2(src[0], src[256]);
        }
        for (int j = tid; j < 640; j += 512)
            *(short8*)&ewl[j*8] = *(const short8*)&wpe[(cc*128)*40 + j*8];
        __syncthreads();
        short8 A[8];
        #pragma unroll
        for (int mf = 0; mf < 8; ++mf)
            A[mf] = *(const short8*)&ewl[(mf*16 + ln)*40 + kg*8];
        #pragma unroll
        for (int nf = 0; nf < 2; ++nf){
            short8 B = *(const short8*)&xbl[(wid*32 + nf*16 + ln)*40 + kg*8];
            #pragma unroll
            for (int mf = 0; mf < 8; ++mf)
                ae[mf][nf] = MFMA(A[mf], B, ae[mf][nf]);
        }
    }
    // emb -> LDS (bias added here, pre-Gram, matching reference)
    #pragma unroll
    for (int mf = 0; mf < 8; ++mf){
        int e0 = mf*16 + kg*4;
        float4 bv = *(const float4*)&eb[e0];
        #pragma unroll
        for (int nf = 0; nf < 2; ++nf){
            int px = wid*32 + nf*16 + ln;
            f32x4 a = ae[mf][nf];
            ushort4 st;
            st.x = f2b(a[0] + bv.x); st.y = f2b(a[1] + bv.y);
            st.z = f2b(a[2] + bv.z); st.w = f2b(a[3] + bv.w);
            *(ushort4*)&embl[px*136 + e0] = st;
        }
    }
    __syncthreads();

    const int wq = wid >> 2, wi = wid & 3;   // wave = 128q x 64i
    f32x4 g[8][4];
    #pragma unroll
    for (int mf = 0; mf < 8; ++mf)
        #pragma unroll
        for (int nf = 0; nf < 4; ++nf) g[mf][nf] = zero4;

    #pragma unroll
    for (int ks = 0; ks < 4; ++ks){
        short8 A[8];
        #pragma unroll
        for (int mf = 0; mf < 8; ++mf)
            A[mf] = *(const short8*)&embl[(wq*128 + mf*16 + ln)*136 + ks*32 + kg*8];
        #pragma unroll
        for (int nf = 0; nf < 4; ++nf){
            short8 B = *(const short8*)&embl[(wi*64 + nf*16 + ln)*136 + ks*32 + kg*8];
            #pragma unroll
            for (int mf = 0; mf < 8; ++mf)
                g[mf][nf] = MFMA(A[mf], B, g[mf][nf]);
        }
    }
    const float sc = 0.08838834764831845f;   // 1/sqrt(128)
    #pragma unroll
    for (int mf = 0; mf < 8; ++mf){
        #pragma unroll
        for (int nf = 0; nf < 4; ++nf){
            int i = wi*64 + nf*16 + ln;
            #pragma unroll
            for (int r = 0; r < 4; ++r){
                int q = wq*128 + mf*16 + kg*4 + r;
                vol[(((size_t)b*256 + q)*256) + i] = sigmoidf_(g[mf][nf][r] * sc);
            }
        }
    }
}

// ---------------------------------------------------------------------------
extern "C" void kernel_launch(void* const* d_in, const int* in_sizes, int n_in,
                              void* d_out, int out_size, void* d_ws, size_t ws_size,
                              hipStream_t stream)
{
    const float* x    = (const float*)d_in[0];
    const float* ew   = (const float*)d_in[1];
    const float* eb   = (const float*)d_in[2];
    const float* w1   = (const float*)d_in[3];
    const float* bn1s = (const float*)d_in[4];
    const float* bn1b = (const float*)d_in[5];
    const float* w2   = (const float*)d_in[6];
    const float* bn2s = (const float*)d_in[7];
    const float* bn2b = (const float*)d_in[8];
    const float* wd   = (const float*)d_in[9];
    const float* bnds = (const float*)d_in[10];
    const float* bndb = (const float*)d_in[11];
    const float* w3   = (const float*)d_in[12];
    const float* bn3s = (const float*)d_in[13];
    const float* bn3b = (const float*)d_in[14];
    const float* w4   = (const float*)d_in[15];
    const float* bn4s = (const float*)d_in[16];
    const float* bn4b = (const float*)d_in[17];
    const float* hw   = (const float*)d_in[18];

    float* pred = (float*)d_out;            // [256,200]
    float* vol  = pred + 51200;             // [256,256,256] f32 = 67,108,864 B

    // prepped weights in d_ws (21.0 MB total)
    u16* wp2 = (u16*)d_ws;
    u16* wp3 = wp2 + 2949120;
    u16* wp4 = wp3 + 2949120;
    u16* wp1 = wp4 + 2949120;
    u16* wpd = wp1 + 1474560;
    u16* wpe = wpd + 163840;

    // activations (NHWC bf16, 16,777,216 B each) packed exactly into vol region
    u16* y1 = (u16*)vol;
    u16* y  = y1 + 8388608;
    u16* z1 = y  + 8388608;
    u16* z  = z1 + 8388608;

    prep_kernel<<<41120, 256, 0, stream>>>(w1, bn1s, w2, bn2s, w3, bn3s, w4, bn4s,
                                           wd, bnds, ew, wp1, wp2, wp3, wp4, wpd, wpe);
    conv1_kernel<<<dim3(2,128), 512, 0, stream>>>(x, wp1, bn1b, y1);
    conv_s1_kernel<1,0><<<dim3(4,64), 512, 0, stream>>>(y1, wp2, bn2b, x, wpd, bndb,
                                                        nullptr, y);
    conv_s1_kernel<0,0><<<dim3(4,64), 512, 0, stream>>>(y, wp3, bn3b, nullptr, nullptr,
                                                        nullptr, nullptr, z1);
    conv_s1_kernel<0,1><<<dim3(4,64), 512, 0, stream>>>(z1, wp4, bn4b, nullptr, nullptr,
                                                        nullptr, y, z);
    head_kernel<<<256, 256, 0, stream>>>(z, hw, pred);
    gram_kernel<<<256, 512, 0, stream>>>(x, wpe, eb, vol);
}

// Round 3
// 493.842 us; speedup vs baseline: 22.3351x; 1.1043x over previous
//
#include <hip/hip_runtime.h>

// ---------------------------------------------------------------------------
// SelfConsistNet, bf16 MFMA implicit-GEMM pipeline (NHWC activations), r3.
// Changes vs r2: conv kernels load weight A-fragments DIRECTLY from the
// prepped global layout (no LDS weight buffer) -> LDS 64KB, 2 blocks/CU,
// barriers 48->16 (conv_s1) / 72->8 (conv1); T14 split act staging;
// conv_s1 grid (8 cot,64 bg) so XCD==cot => weights L2-resident.
// ---------------------------------------------------------------------------

using short8 = __attribute__((ext_vector_type(8))) short;   // 8 bf16 (4 VGPR)
using f32x4  = __attribute__((ext_vector_type(4))) float;   // MFMA acc
typedef unsigned short u16;
typedef unsigned int   u32;

#define MFMA(a,b,c) __builtin_amdgcn_mfma_f32_16x16x32_bf16((a),(b),(c),0,0,0)

__device__ __forceinline__ u16 f2b(float f){
    u32 u = __builtin_bit_cast(u32, f);
    u += 0x7FFFu + ((u >> 16) & 1u);        // RNE
    return (u16)(u >> 16);
}
__device__ __forceinline__ float b2f(u16 h){
    u32 u = ((u32)h) << 16;
    return __builtin_bit_cast(float, u);
}
__device__ __forceinline__ u32 pack2(float a, float b){
    return (u32)f2b(a) | ((u32)f2b(b) << 16);
}
__device__ __forceinline__ float sigmoidf_(float v){
    return 1.0f / (1.0f + __expf(-v));
}

// ---------------------------------------------------------------------------
// Weight prep (unchanged from r2): bf16 [dydx][cc][co][40] fragment tiles,
// BN scale folded. One thread per element; 41120*256 threads exactly.
// ---------------------------------------------------------------------------
__global__ __launch_bounds__(256)
void prep_kernel(const float* __restrict__ w1, const float* __restrict__ s1,
                 const float* __restrict__ w2, const float* __restrict__ s2,
                 const float* __restrict__ w3, const float* __restrict__ s3,
                 const float* __restrict__ w4, const float* __restrict__ s4,
                 const float* __restrict__ wd, const float* __restrict__ sd,
                 const float* __restrict__ ew,
                 u16* __restrict__ wp1, u16* __restrict__ wp2,
                 u16* __restrict__ wp3, u16* __restrict__ wp4,
                 u16* __restrict__ wpd, u16* __restrict__ wpe)
{
    const int N2 = 9*16*512*40, N1 = 9*8*512*40, ND = 8*512*40, NE = 8*128*40;
    int t = blockIdx.x * 256 + threadIdx.x;
    if (t < N2) {
        int j = t % 40; int r = t / 40; int co = r & 511; int q = r >> 9;
        int cc = q & 15; int dydx = q >> 4;
        float v = (j < 32) ? w2[(co*512 + cc*32 + j)*9 + dydx] * s2[co] : 0.f;
        wp2[t] = f2b(v); return;
    }
    t -= N2;
    if (t < N2) {
        int j = t % 40; int r = t / 40; int co = r & 511; int q = r >> 9;
        int cc = q & 15; int dydx = q >> 4;
        float v = (j < 32) ? w3[(co*512 + cc*32 + j)*9 + dydx] * s3[co] : 0.f;
        wp3[t] = f2b(v); return;
    }
    t -= N2;
    if (t < N2) {
        int j = t % 40; int r = t / 40; int co = r & 511; int q = r >> 9;
        int cc = q & 15; int dydx = q >> 4;
        float v = (j < 32) ? w4[(co*512 + cc*32 + j)*9 + dydx] * s4[co] : 0.f;
        wp4[t] = f2b(v); return;
    }
    t -= N2;
    if (t < N1) {
        int j = t % 40; int r = t / 40; int co = r & 511; int q = r >> 9;
        int cc = q & 7; int dydx = q >> 3;
        float v = (j < 32) ? w1[(co*256 + cc*32 + j)*9 + dydx] * s1[co] : 0.f;
        wp1[t] = f2b(v); return;
    }
    t -= N1;
    if (t < ND) {
        int j = t % 40; int r = t / 40; int co = r & 511; int cc = r >> 9;
        float v = (j < 32) ? wd[co*256 + cc*32 + j] * sd[co] : 0.f;
        wpd[t] = f2b(v); return;
    }
    t -= ND;
    if (t < NE) {
        int j = t % 40; int r = t / 40; int e = r & 127; int cc = r >> 7;
        float v = (j < 32) ? ew[e*256 + cc*32 + j] : 0.f;
        wpe[t] = f2b(v);
    }
}

// ---------------------------------------------------------------------------
// K1: conv3x3 s2, x NCHW f32 -> y1 NHWC bf16. grid (2 cot=256co, 128 bpair),
// 512 thr = 8 waves (wco 0..3 x bb 0..1). Weights direct-from-global;
// LDS = act only (92,480 B, dbuf 17x17-padded planes); 8 barriers.
// ---------------------------------------------------------------------------
__global__ __launch_bounds__(512, 2)
void conv1_kernel(const float* __restrict__ x, const u16* __restrict__ wp,
                  const float* __restrict__ bnb, u16* __restrict__ out)
{
    const int cot = blockIdx.x;          // 0..1
    const int b0  = blockIdx.y * 2;
    const int tid = threadIdx.x;
    const int wid = tid >> 6, lane = tid & 63;
    const int ln = lane & 15, kg = lane >> 4;
    const int wco = wid >> 1;            // 0..3
    const int bb  = wid & 1;             // 0..1

    __shared__ u16 actb[2][2*289*40];    // 92,480 B

    {
        short8 zz = {0,0,0,0,0,0,0,0};
        short8* ab = (short8*)&actb[0][0];
        for (int j = tid; j < 2*2*289*40/8; j += 512) ab[j] = zz;
    }
    __syncthreads();

    auto stage_act = [&](int cc, int p){
        #pragma unroll
        for (int it = 0; it < 16; ++it){
            int f = it*512 + tid;                    // 8192 dwords
            int bb2 = f >> 12; int rem = f & 4095;
            int cip = rem >> 8; int px = rem & 255;
            const float* src = &x[(((size_t)(b0+bb2)*256 + cc*32 + 2*cip)*256) + px];
            float v0 = src[0], v1 = src[256];
            int r = ((px >> 4) + 1)*17 + (px & 15) + 1;
            *(u32*)&actb[p][(bb2*289 + r)*40 + 2*cip] = pack2(v0, v1);
        }
    };

    stage_act(0, 0);
    __syncthreads();

    f32x4 zero4 = {0.f,0.f,0.f,0.f};
    f32x4 acc[4][4];
    #pragma unroll
    for (int mf = 0; mf < 4; ++mf)
        #pragma unroll
        for (int nf = 0; nf < 4; ++nf) acc[mf][nf] = zero4;

    int bbase[4];
    #pragma unroll
    for (int nf = 0; nf < 4; ++nf){
        int px = nf*16 + ln;
        bbase[nf] = (bb*289 + 34*(px>>3) + 2*(px&7))*40 + kg*8;
    }

    for (int cc = 0; cc < 8; ++cc){
        if (cc < 7) stage_act(cc+1, (cc+1) & 1);
        const u16* abp = actb[cc & 1];
        #pragma unroll
        for (int d = 0; d < 9; ++d){
            const u16* wdp = wp + ((size_t)(d*8 + cc)*512 + cot*256)*40;
            int dy = d/3, dx = d - dy*3;
            int shift = (dy*17 + dx)*40;
            short8 A[4];
            #pragma unroll
            for (int mf = 0; mf < 4; ++mf)
                A[mf] = *(const short8*)&wdp[(wco*64 + mf*16 + ln)*40 + kg*8];
            #pragma unroll
            for (int nf = 0; nf < 4; ++nf){
                short8 B = *(const short8*)&abp[bbase[nf] + shift];
                #pragma unroll
                for (int mf = 0; mf < 4; ++mf)
                    acc[mf][nf] = MFMA(A[mf], B, acc[mf][nf]);
            }
        }
        __syncthreads();
    }

    #pragma unroll
    for (int mf = 0; mf < 4; ++mf){
        int co0 = cot*256 + wco*64 + mf*16 + kg*4;
        float4 bv = *(const float4*)&bnb[co0];
        #pragma unroll
        for (int nf = 0; nf < 4; ++nf){
            int px = nf*16 + ln;
            size_t o = (((size_t)(b0+bb)*64) + px)*512 + co0;
            f32x4 a = acc[mf][nf];
            ushort4 st;
            st.x = f2b(fmaxf(a[0] + bv.x, 0.f));
            st.y = f2b(fmaxf(a[1] + bv.y, 0.f));
            st.z = f2b(fmaxf(a[2] + bv.z, 0.f));
            st.w = f2b(fmaxf(a[3] + bv.w, 0.f));
            *(ushort4*)&out[o] = st;
        }
    }
}

// ---------------------------------------------------------------------------
// K2/K3/K4: conv3x3 s1 on 8x8 NHWC bf16, Cin=Cout=512; weights direct from
// global (fragment-tiled), LDS = act only 64,000 B -> 2 blocks/CU.
// grid (8 cot=64co, 64 bg=4 batches); 512 thr = 8 waves (bb 0..3 x ph 0..1);
// per wave 64co x 32px (mf=4, nf=2). 16 barriers (1/cc), T14 split staging.
// XCD==cot (gridDim.x=8) => per-XCD weight set 0.74MB, L2-resident.
// ---------------------------------------------------------------------------
template<int DOWN, int RES>
__global__ __launch_bounds__(512, 4)
void conv_s1_kernel(const u16* __restrict__ in, const u16* __restrict__ wp,
                    const float* __restrict__ bnb,
                    const float* __restrict__ x, const u16* __restrict__ wpd,
                    const float* __restrict__ dbb,
                    const u16* __restrict__ res, u16* __restrict__ out)
{
    const int cot = blockIdx.x;          // 0..7
    const int b0  = blockIdx.y * 4;
    const int tid = threadIdx.x;
    const int wid = tid >> 6, lane = tid & 63;
    const int ln = lane & 15, kg = lane >> 4;
    const int bb = wid >> 1;             // 0..3 (batch)
    const int ph = wid & 1;              // 0..1 (px half)

    __shared__ u16 actb[2][4*100*40];    // 64,000 B total

    {
        short8 zz = {0,0,0,0,0,0,0,0};
        short8* ab = (short8*)&actb[0][0];
        for (int j = tid; j < 2*4*100*40/8; j += 512) ab[j] = zz;
    }
    __syncthreads();

    const int j0 = tid, j1 = 512 + tid;            // 1024 short8 per stage
    const int s_bb0 = j0 >> 8, s_px0 = (j0 & 255) >> 2, s_cg0 = j0 & 3;
    const int s_bb1 = j1 >> 8, s_px1 = (j1 & 255) >> 2, s_cg1 = j1 & 3;
    const int s_ld0 = ((s_bb0*100 + ((s_px0>>3)+1)*10 + (s_px0&7) + 1))*40 + s_cg0*8;
    const int s_ld1 = ((s_bb1*100 + ((s_px1>>3)+1)*10 + (s_px1&7) + 1))*40 + s_cg1*8;

    short8 sreg0, sreg1;
    auto stage_load = [&](int cc){
        sreg0 = *(const short8*)&in[(((size_t)(b0+s_bb0)*64 + s_px0)*512) + cc*32 + s_cg0*8];
        sreg1 = *(const short8*)&in[(((size_t)(b0+s_bb1)*64 + s_px1)*512) + cc*32 + s_cg1*8];
    };
    auto stage_store = [&](int p){
        *(short8*)&actb[p][s_ld0] = sreg0;
        *(short8*)&actb[p][s_ld1] = sreg1;
    };

    stage_load(0); stage_store(0);
    __syncthreads();

    f32x4 zero4 = {0.f,0.f,0.f,0.f};
    f32x4 acc[4][2];
    #pragma unroll
    for (int mf = 0; mf < 4; ++mf){ acc[mf][0] = zero4; acc[mf][1] = zero4; }

    int bbase[2];
    #pragma unroll
    for (int nf = 0; nf < 2; ++nf){
        int px = ph*32 + nf*16 + ln;
        bbase[nf] = (bb*100 + (px>>3)*10 + (px&7))*40 + kg*8;
    }
    const int aoff = ln*40 + kg*8;

    for (int cc = 0; cc < 16; ++cc){
        if (cc < 15) stage_load(cc+1);
        const u16* abp = actb[cc & 1];
        #pragma unroll
        for (int dy = 0; dy < 3; ++dy){
            #pragma unroll
            for (int dx = 0; dx < 3; ++dx){
                const u16* wdp = wp + ((size_t)((dy*3+dx)*16 + cc)*512 + cot*64)*40;
                short8 A[4];
                #pragma unroll
                for (int mf = 0; mf < 4; ++mf)
                    A[mf] = *(const short8*)&wdp[mf*640 + aoff];
                int shift = (dy*10 + dx)*40;
                #pragma unroll
                for (int nf = 0; nf < 2; ++nf){
                    short8 B = *(const short8*)&abp[bbase[nf] + shift];
                    #pragma unroll
                    for (int mf = 0; mf < 4; ++mf)
                        acc[mf][nf] = MFMA(A[mf], B, acc[mf][nf]);
                }
            }
        }
        if (cc < 15){
            stage_store((cc+1) & 1);
            __syncthreads();
        }
    }

    if (DOWN){
        // fused 1x1 stride-2 downsample from x (NCHW f32), K=256 in 8 chunks,
        // single-buffered in actb[0] (first 4*64*40 elems).
        for (int dc = 0; dc < 8; ++dc){
            __syncthreads();
            #pragma unroll
            for (int it = 0; it < 8; ++it){
                int f = it*512 + tid;                // 4096 dwords
                int bb2 = f >> 10; int rem = f & 1023;
                int cip = rem >> 6, px = rem & 63;
                int ipx = (px>>3)*32 + (px&7)*2;
                const float* src = &x[(((size_t)(b0+bb2)*256 + dc*32 + 2*cip)*256) + ipx];
                *(u32*)&actb[0][(bb2*64 + px)*40 + 2*cip] = pack2(src[0], src[256]);
            }
            __syncthreads();
            const u16* wdp = wpd + ((size_t)dc*512 + cot*64)*40;
            short8 A[4];
            #pragma unroll
            for (int mf = 0; mf < 4; ++mf)
                A[mf] = *(const short8*)&wdp[mf*640 + aoff];
            #pragma unroll
            for (int nf = 0; nf < 2; ++nf){
                short8 B = *(const short8*)&actb[0][(bb*64 + ph*32 + nf*16 + ln)*40 + kg*8];
                #pragma unroll
                for (int mf = 0; mf < 4; ++mf)
                    acc[mf][nf] = MFMA(A[mf], B, acc[mf][nf]);
            }
        }
    }

    #pragma unroll
    for (int mf = 0; mf < 4; ++mf){
        int co0 = cot*64 + mf*16 + kg*4;
        float4 bv = *(const float4*)&bnb[co0];
        if (DOWN){
            float4 dv = *(const float4*)&dbb[co0];
            bv.x += dv.x; bv.y += dv.y; bv.z += dv.z; bv.w += dv.w;
        }
        #pragma unroll
        for (int nf = 0; nf < 2; ++nf){
            int px = ph*32 + nf*16 + ln;
            size_t o = (((size_t)(b0+bb)*64) + px)*512 + co0;
            f32x4 a = acc[mf][nf];
            float v0 = a[0] + bv.x, v1 = a[1] + bv.y;
            float v2 = a[2] + bv.z, v3 = a[3] + bv.w;
            if (RES){
                ushort4 rv = *(const ushort4*)&res[o];
                v0 += b2f(rv.x); v1 += b2f(rv.y); v2 += b2f(rv.z); v3 += b2f(rv.w);
            }
            ushort4 st;
            st.x = f2b(fmaxf(v0, 0.f)); st.y = f2b(fmaxf(v1, 0.f));
            st.z = f2b(fmaxf(v2, 0.f)); st.w = f2b(fmaxf(v3, 0.f));
            *(ushort4*)&out[o] = st;
        }
    }
}

// ---------------------------------------------------------------------------
// head: GAP(8x8) + linear 512->200. z NHWC bf16. One block per batch.
// ---------------------------------------------------------------------------
__global__ __launch_bounds__(256)
void head_kernel(const u16* __restrict__ z, const float* __restrict__ hw,
                 float* __restrict__ pred)
{
    const int b = blockIdx.x, tid = threadIdx.x;
    __shared__ float feat[512];
    float s0 = 0.f, s1 = 0.f;
    for (int px = 0; px < 64; ++px){
        u32 u = *(const u32*)&z[(((size_t)b*64 + px)*512) + 2*tid];
        s0 += b2f((u16)(u & 0xFFFF));
        s1 += b2f((u16)(u >> 16));
    }
    feat[2*tid]   = s0 * (1.f/64.f);
    feat[2*tid+1] = s1 * (1.f/64.f);
    __syncthreads();
    if (tid < 200){
        float acc = 0.f;
        const float4* hp = (const float4*)&hw[(size_t)tid*512];
        #pragma unroll 8
        for (int i = 0; i < 128; ++i){
            float4 h = hp[i];
            float4 f = *(const float4*)&feat[i*4];
            acc += h.x*f.x + h.y*f.y + h.z*f.z + h.w*f.w;
        }
        pred[b*200 + tid] = acc;
    }
}

// ---------------------------------------------------------------------------
// gram: fused embed (emb LDS-resident) + Gram + sigmoid. 1 block/batch.
// ---------------------------------------------------------------------------
__global__ __launch_bounds__(512, 2)
void gram_kernel(const float* __restrict__ x, const u16* __restrict__ wpe,
                 const float* __restrict__ eb, float* __restrict__ vol)
{
    const int b = blockIdx.x, tid = threadIdx.x;
    const int wid = tid >> 6, lane = tid & 63;
    const int ln = lane & 15, kg = lane >> 4;

    __shared__ u16 embl[256*136];        // 69,632 B
    __shared__ u16 xbl[256*40];          // 20,480 B
    __shared__ u16 ewl[128*40];          // 10,240 B

    f32x4 zero4 = {0.f,0.f,0.f,0.f};
    f32x4 ae[8][2];
    #pragma unroll
    for (int mf = 0; mf < 8; ++mf){ ae[mf][0] = zero4; ae[mf][1] = zero4; }

    for (int cc = 0; cc < 8; ++cc){
        __syncthreads();
        #pragma unroll
        for (int it = 0; it < 8; ++it){
            int f = it*512 + tid;
            int cip = f >> 8, px = f & 255;
            const float* src = &x[(((size_t)b*256 + cc*32 + 2*cip)*256) + px];
            *(u32*)&xbl[px*40 + 2*cip] = pack2(src[0], src[256]);
        }
        for (int j = tid; j < 640; j += 512)
            *(short8*)&ewl[j*8] = *(const short8*)&wpe[(cc*128)*40 + j*8];
        __syncthreads();
        short8 A[8];
        #pragma unroll
        for (int mf = 0; mf < 8; ++mf)
            A[mf] = *(const short8*)&ewl[(mf*16 + ln)*40 + kg*8];
        #pragma unroll
        for (int nf = 0; nf < 2; ++nf){
            short8 B = *(const short8*)&xbl[(wid*32 + nf*16 + ln)*40 + kg*8];
            #pragma unroll
            for (int mf = 0; mf < 8; ++mf)
                ae[mf][nf] = MFMA(A[mf], B, ae[mf][nf]);
        }
    }
    #pragma unroll
    for (int mf = 0; mf < 8; ++mf){
        int e0 = mf*16 + kg*4;
        float4 bv = *(const float4*)&eb[e0];
        #pragma unroll
        for (int nf = 0; nf < 2; ++nf){
            int px = wid*32 + nf*16 + ln;
            f32x4 a = ae[mf][nf];
            ushort4 st;
            st.x = f2b(a[0] + bv.x); st.y = f2b(a[1] + bv.y);
            st.z = f2b(a[2] + bv.z); st.w = f2b(a[3] + bv.w);
            *(ushort4*)&embl[px*136 + e0] = st;
        }
    }
    __syncthreads();

    const int wq = wid >> 2, wi = wid & 3;
    f32x4 g[8][4];
    #pragma unroll
    for (int mf = 0; mf < 8; ++mf)
        #pragma unroll
        for (int nf = 0; nf < 4; ++nf) g[mf][nf] = zero4;

    #pragma unroll
    for (int ks = 0; ks < 4; ++ks){
        short8 A[8];
        #pragma unroll
        for (int mf = 0; mf < 8; ++mf)
            A[mf] = *(const short8*)&embl[(wq*128 + mf*16 + ln)*136 + ks*32 + kg*8];
        #pragma unroll
        for (int nf = 0; nf < 4; ++nf){
            short8 B = *(const short8*)&embl[(wi*64 + nf*16 + ln)*136 + ks*32 + kg*8];
            #pragma unroll
            for (int mf = 0; mf < 8; ++mf)
                g[mf][nf] = MFMA(A[mf], B, g[mf][nf]);
        }
    }
    const float sc = 0.08838834764831845f;   // 1/sqrt(128)
    #pragma unroll
    for (int mf = 0; mf < 8; ++mf){
        #pragma unroll
        for (int nf = 0; nf < 4; ++nf){
            int i = wi*64 + nf*16 + ln;
            #pragma unroll
            for (int r = 0; r < 4; ++r){
                int q = wq*128 + mf*16 + kg*4 + r;
                vol[(((size_t)b*256 + q)*256) + i] = sigmoidf_(g[mf][nf][r] * sc);
            }
        }
    }
}

// ---------------------------------------------------------------------------
extern "C" void kernel_launch(void* const* d_in, const int* in_sizes, int n_in,
                              void* d_out, int out_size, void* d_ws, size_t ws_size,
                              hipStream_t stream)
{
    const float* x    = (const float*)d_in[0];
    const float* ew   = (const float*)d_in[1];
    const float* eb   = (const float*)d_in[2];
    const float* w1   = (const float*)d_in[3];
    const float* bn1s = (const float*)d_in[4];
    const float* bn1b = (const float*)d_in[5];
    const float* w2   = (const float*)d_in[6];
    const float* bn2s = (const float*)d_in[7];
    const float* bn2b = (const float*)d_in[8];
    const float* wd   = (const float*)d_in[9];
    const float* bnds = (const float*)d_in[10];
    const float* bndb = (const float*)d_in[11];
    const float* w3   = (const float*)d_in[12];
    const float* bn3s = (const float*)d_in[13];
    const float* bn3b = (const float*)d_in[14];
    const float* w4   = (const float*)d_in[15];
    const float* bn4s = (const float*)d_in[16];
    const float* bn4b = (const float*)d_in[17];
    const float* hw   = (const float*)d_in[18];

    float* pred = (float*)d_out;            // [256,200]
    float* vol  = pred + 51200;             // [256,256,256] f32

    u16* wp2 = (u16*)d_ws;
    u16* wp3 = wp2 + 2949120;
    u16* wp4 = wp3 + 2949120;
    u16* wp1 = wp4 + 2949120;
    u16* wpd = wp1 + 1474560;
    u16* wpe = wpd + 163840;

    u16* y1 = (u16*)vol;
    u16* y  = y1 + 8388608;
    u16* z1 = y  + 8388608;
    u16* z  = z1 + 8388608;

    prep_kernel<<<41120, 256, 0, stream>>>(w1, bn1s, w2, bn2s, w3, bn3s, w4, bn4s,
                                           wd, bnds, ew, wp1, wp2, wp3, wp4, wpd, wpe);
    conv1_kernel<<<dim3(2,128), 512, 0, stream>>>(x, wp1, bn1b, y1);
    conv_s1_kernel<1,0><<<dim3(8,64), 512, 0, stream>>>(y1, wp2, bn2b, x, wpd, bndb,
                                                        nullptr, y);
    conv_s1_kernel<0,0><<<dim3(8,64), 512, 0, stream>>>(y, wp3, bn3b, nullptr, nullptr,
                                                        nullptr, nullptr, z1);
    conv_s1_kernel<0,1><<<dim3(8,64), 512, 0, stream>>>(z1, wp4, bn4b, nullptr, nullptr,
                                                        nullptr, y, z);
    head_kernel<<<256, 256, 0, stream>>>(z, hw, pred);
    gram_kernel<<<256, 512, 0, stream>>>(x, wpe, eb, vol);
}

// Round 4
// 448.663 us; speedup vs baseline: 24.5842x; 1.1007x over previous
//
#include <hip/hip_runtime.h>

// ---------------------------------------------------------------------------
// SelfConsistNet, bf16 MFMA implicit-GEMM pipeline (NHWC activations), r4.
// Changes vs r3 (conv_s1 only):
//  - grid (bg=128, cot=8): XCD = bg%8 -> per-XCD act 2.1MB L2-resident,
//    weight phase-slice ~300KB; act reused 8x in L2.
//  - 256-thr blocks (4 waves, 2 batches), LDS 32KB -> 4 blocks/CU.
//  - A-fragments preloaded 12-deep per dy (latency amortization).
//  - XOR bank-swizzle on act LDS (slot = kg ^ ((row>>3)&3)) kills the
//    measured period-8/16 pixel-row bank collisions.
// ---------------------------------------------------------------------------

using short8 = __attribute__((ext_vector_type(8))) short;   // 8 bf16 (4 VGPR)
using f32x4  = __attribute__((ext_vector_type(4))) float;   // MFMA acc
typedef unsigned short u16;
typedef unsigned int   u32;

#define MFMA(a,b,c) __builtin_amdgcn_mfma_f32_16x16x32_bf16((a),(b),(c),0,0,0)

__device__ __forceinline__ u16 f2b(float f){
    u32 u = __builtin_bit_cast(u32, f);
    u += 0x7FFFu + ((u >> 16) & 1u);        // RNE
    return (u16)(u >> 16);
}
__device__ __forceinline__ float b2f(u16 h){
    u32 u = ((u32)h) << 16;
    return __builtin_bit_cast(float, u);
}
__device__ __forceinline__ u32 pack2(float a, float b){
    return (u32)f2b(a) | ((u32)f2b(b) << 16);
}
__device__ __forceinline__ float sigmoidf_(float v){
    return 1.0f / (1.0f + __expf(-v));
}

// ---------------------------------------------------------------------------
// Weight prep (unchanged): bf16 [dydx][cc][co][40] fragment tiles, BN folded.
// ---------------------------------------------------------------------------
__global__ __launch_bounds__(256)
void prep_kernel(const float* __restrict__ w1, const float* __restrict__ s1,
                 const float* __restrict__ w2, const float* __restrict__ s2,
                 const float* __restrict__ w3, const float* __restrict__ s3,
                 const float* __restrict__ w4, const float* __restrict__ s4,
                 const float* __restrict__ wd, const float* __restrict__ sd,
                 const float* __restrict__ ew,
                 u16* __restrict__ wp1, u16* __restrict__ wp2,
                 u16* __restrict__ wp3, u16* __restrict__ wp4,
                 u16* __restrict__ wpd, u16* __restrict__ wpe)
{
    const int N2 = 9*16*512*40, N1 = 9*8*512*40, ND = 8*512*40, NE = 8*128*40;
    int t = blockIdx.x * 256 + threadIdx.x;
    if (t < N2) {
        int j = t % 40; int r = t / 40; int co = r & 511; int q = r >> 9;
        int cc = q & 15; int dydx = q >> 4;
        float v = (j < 32) ? w2[(co*512 + cc*32 + j)*9 + dydx] * s2[co] : 0.f;
        wp2[t] = f2b(v); return;
    }
    t -= N2;
    if (t < N2) {
        int j = t % 40; int r = t / 40; int co = r & 511; int q = r >> 9;
        int cc = q & 15; int dydx = q >> 4;
        float v = (j < 32) ? w3[(co*512 + cc*32 + j)*9 + dydx] * s3[co] : 0.f;
        wp3[t] = f2b(v); return;
    }
    t -= N2;
    if (t < N2) {
        int j = t % 40; int r = t / 40; int co = r & 511; int q = r >> 9;
        int cc = q & 15; int dydx = q >> 4;
        float v = (j < 32) ? w4[(co*512 + cc*32 + j)*9 + dydx] * s4[co] : 0.f;
        wp4[t] = f2b(v); return;
    }
    t -= N2;
    if (t < N1) {
        int j = t % 40; int r = t / 40; int co = r & 511; int q = r >> 9;
        int cc = q & 7; int dydx = q >> 3;
        float v = (j < 32) ? w1[(co*256 + cc*32 + j)*9 + dydx] * s1[co] : 0.f;
        wp1[t] = f2b(v); return;
    }
    t -= N1;
    if (t < ND) {
        int j = t % 40; int r = t / 40; int co = r & 511; int cc = r >> 9;
        float v = (j < 32) ? wd[co*256 + cc*32 + j] * sd[co] : 0.f;
        wpd[t] = f2b(v); return;
    }
    t -= ND;
    if (t < NE) {
        int j = t % 40; int r = t / 40; int e = r & 127; int cc = r >> 7;
        float v = (j < 32) ? ew[e*256 + cc*32 + j] : 0.f;
        wpe[t] = f2b(v);
    }
}

// ---------------------------------------------------------------------------
// K1: conv3x3 s2 (unchanged from r3).
// ---------------------------------------------------------------------------
__global__ __launch_bounds__(512, 2)
void conv1_kernel(const float* __restrict__ x, const u16* __restrict__ wp,
                  const float* __restrict__ bnb, u16* __restrict__ out)
{
    const int cot = blockIdx.x;          // 0..1
    const int b0  = blockIdx.y * 2;
    const int tid = threadIdx.x;
    const int wid = tid >> 6, lane = tid & 63;
    const int ln = lane & 15, kg = lane >> 4;
    const int wco = wid >> 1;            // 0..3
    const int bb  = wid & 1;             // 0..1

    __shared__ u16 actb[2][2*289*40];    // 92,480 B

    {
        short8 zz = {0,0,0,0,0,0,0,0};
        short8* ab = (short8*)&actb[0][0];
        for (int j = tid; j < 2*2*289*40/8; j += 512) ab[j] = zz;
    }
    __syncthreads();

    auto stage_act = [&](int cc, int p){
        #pragma unroll
        for (int it = 0; it < 16; ++it){
            int f = it*512 + tid;                    // 8192 dwords
            int bb2 = f >> 12; int rem = f & 4095;
            int cip = rem >> 8; int px = rem & 255;
            const float* src = &x[(((size_t)(b0+bb2)*256 + cc*32 + 2*cip)*256) + px];
            float v0 = src[0], v1 = src[256];
            int r = ((px >> 4) + 1)*17 + (px & 15) + 1;
            *(u32*)&actb[p][(bb2*289 + r)*40 + 2*cip] = pack2(v0, v1);
        }
    };

    stage_act(0, 0);
    __syncthreads();

    f32x4 zero4 = {0.f,0.f,0.f,0.f};
    f32x4 acc[4][4];
    #pragma unroll
    for (int mf = 0; mf < 4; ++mf)
        #pragma unroll
        for (int nf = 0; nf < 4; ++nf) acc[mf][nf] = zero4;

    int bbase[4];
    #pragma unroll
    for (int nf = 0; nf < 4; ++nf){
        int px = nf*16 + ln;
        bbase[nf] = (bb*289 + 34*(px>>3) + 2*(px&7))*40 + kg*8;
    }

    for (int cc = 0; cc < 8; ++cc){
        if (cc < 7) stage_act(cc+1, (cc+1) & 1);
        const u16* abp = actb[cc & 1];
        #pragma unroll
        for (int d = 0; d < 9; ++d){
            const u16* wdp = wp + ((size_t)(d*8 + cc)*512 + cot*256)*40;
            int dy = d/3, dx = d - dy*3;
            int shift = (dy*17 + dx)*40;
            short8 A[4];
            #pragma unroll
            for (int mf = 0; mf < 4; ++mf)
                A[mf] = *(const short8*)&wdp[(wco*64 + mf*16 + ln)*40 + kg*8];
            #pragma unroll
            for (int nf = 0; nf < 4; ++nf){
                short8 B = *(const short8*)&abp[bbase[nf] + shift];
                #pragma unroll
                for (int mf = 0; mf < 4; ++mf)
                    acc[mf][nf] = MFMA(A[mf], B, acc[mf][nf]);
            }
        }
        __syncthreads();
    }

    #pragma unroll
    for (int mf = 0; mf < 4; ++mf){
        int co0 = cot*256 + wco*64 + mf*16 + kg*4;
        float4 bv = *(const float4*)&bnb[co0];
        #pragma unroll
        for (int nf = 0; nf < 4; ++nf){
            int px = nf*16 + ln;
            size_t o = (((size_t)(b0+bb)*64) + px)*512 + co0;
            f32x4 a = acc[mf][nf];
            ushort4 st;
            st.x = f2b(fmaxf(a[0] + bv.x, 0.f));
            st.y = f2b(fmaxf(a[1] + bv.y, 0.f));
            st.z = f2b(fmaxf(a[2] + bv.z, 0.f));
            st.w = f2b(fmaxf(a[3] + bv.w, 0.f));
            *(ushort4*)&out[o] = st;
        }
    }
}

// ---------------------------------------------------------------------------
// K2/K3/K4 (r4): 256 thr = 4 waves (bb 0..1 x ph 0..1); block = 64co x 2batch.
// grid (bg=128, cot=8) -> XCD = bg%8. act LDS dbuf 32,000 B, XOR-swizzled.
// A-frags direct from global, preloaded 12-deep per dy. 16 barriers.
// ---------------------------------------------------------------------------
template<int DOWN, int RES>
__global__ __launch_bounds__(256, 4)
void conv_s1_kernel(const u16* __restrict__ in, const u16* __restrict__ wp,
                    const float* __restrict__ bnb,
                    const float* __restrict__ x, const u16* __restrict__ wpd,
                    const float* __restrict__ dbb,
                    const u16* __restrict__ res, u16* __restrict__ out)
{
    const int bg  = blockIdx.x;          // 0..127 (XCD = bg%8)
    const int cot = blockIdx.y;          // 0..7
    const int b0  = bg * 2;
    const int tid = threadIdx.x;
    const int wid = tid >> 6, lane = tid & 63;
    const int ln = lane & 15, kg = lane >> 4;
    const int bb = wid >> 1;             // 0..1 (batch)
    const int ph = wid & 1;              // 0..1 (px half)

    __shared__ u16 actb[2][2*100*40];    // 32,000 B total

    {
        short8 zz = {0,0,0,0,0,0,0,0};
        short8* ab = (short8*)&actb[0][0];
        for (int j = tid; j < 2*2*100*40/8; j += 256) ab[j] = zz;
    }
    __syncthreads();

    // staging: 512 short8 per cc-chunk, 2 per thread; XOR-swizzled slot
    const int s_px = tid >> 2, s_cg = tid & 3;
    const int row0 = ((s_px>>3)+1)*10 + (s_px&7) + 1;          // batch 0
    const int row1 = 100 + row0;                               // batch 1
    const int s_ld0 = row0*40 + ((s_cg ^ ((row0>>3)&3)))*8;
    const int s_ld1 = row1*40 + ((s_cg ^ ((row1>>3)&3)))*8;

    short8 sreg0, sreg1;
    auto stage_load = [&](int cc){
        sreg0 = *(const short8*)&in[(((size_t)(b0+0)*64 + s_px)*512) + cc*32 + s_cg*8];
        sreg1 = *(const short8*)&in[(((size_t)(b0+1)*64 + s_px)*512) + cc*32 + s_cg*8];
    };
    auto stage_store = [&](int p){
        *(short8*)&actb[p][s_ld0] = sreg0;
        *(short8*)&actb[p][s_ld1] = sreg1;
    };

    stage_load(0); stage_store(0);
    __syncthreads();

    f32x4 zero4 = {0.f,0.f,0.f,0.f};
    f32x4 acc[4][2];
    #pragma unroll
    for (int mf = 0; mf < 4; ++mf){ acc[mf][0] = zero4; acc[mf][1] = zero4; }

    int p0[2];
    #pragma unroll
    for (int nf = 0; nf < 2; ++nf){
        int px = ph*32 + nf*16 + ln;
        p0[nf] = bb*100 + (px>>3)*10 + (px&7);
    }
    const int aoff = ln*40 + kg*8;

    for (int cc = 0; cc < 16; ++cc){
        if (cc < 15) stage_load(cc+1);
        const u16* abp = actb[cc & 1];
        #pragma unroll
        for (int dy = 0; dy < 3; ++dy){
            // preload all 12 A-fragments for this dy (3 dx x 4 mf)
            short8 A[3][4];
            #pragma unroll
            for (int dx = 0; dx < 3; ++dx){
                const u16* wdp = wp + ((size_t)((dy*3+dx)*16 + cc)*512 + cot*64)*40;
                #pragma unroll
                for (int mf = 0; mf < 4; ++mf)
                    A[dx][mf] = *(const short8*)&wdp[mf*640 + aoff];
            }
            #pragma unroll
            for (int dx = 0; dx < 3; ++dx){
                #pragma unroll
                for (int nf = 0; nf < 2; ++nf){
                    int row = p0[nf] + dy*10 + dx;
                    short8 B = *(const short8*)&abp[row*40 + ((kg ^ ((row>>3)&3)))*8];
                    #pragma unroll
                    for (int mf = 0; mf < 4; ++mf)
                        acc[mf][nf] = MFMA(A[dx][mf], B, acc[mf][nf]);
                }
            }
        }
        if (cc < 15){
            stage_store((cc+1) & 1);
            __syncthreads();
        }
    }

    if (DOWN){
        // fused 1x1 stride-2 downsample from x (NCHW f32), K=256 in 8 chunks
        for (int dc = 0; dc < 8; ++dc){
            __syncthreads();
            #pragma unroll
            for (int it = 0; it < 8; ++it){
                int f = it*256 + tid;                // 2048 dword-pairs
                int bb2 = f >> 10; int rem = f & 1023;
                int cip = rem >> 6, px = rem & 63;
                int ipx = (px>>3)*32 + (px&7)*2;
                const float* src = &x[(((size_t)(b0+bb2)*256 + dc*32 + 2*cip)*256) + ipx];
                int rd = bb2*64 + px;
                int el = rd*40 + (((cip>>2) ^ ((rd>>3)&3)))*8 + (cip&3)*2;
                *(u32*)&actb[0][el] = pack2(src[0], src[256]);
            }
            __syncthreads();
            const u16* wdp = wpd + ((size_t)dc*512 + cot*64)*40;
            short8 A[4];
            #pragma unroll
            for (int mf = 0; mf < 4; ++mf)
                A[mf] = *(const short8*)&wdp[mf*640 + aoff];
            #pragma unroll
            for (int nf = 0; nf < 2; ++nf){
                int rd = bb*64 + ph*32 + nf*16 + ln;
                short8 B = *(const short8*)&actb[0][rd*40 + ((kg ^ ((rd>>3)&3)))*8];
                #pragma unroll
                for (int mf = 0; mf < 4; ++mf)
                    acc[mf][nf] = MFMA(A[mf], B, acc[mf][nf]);
            }
        }
    }

    #pragma unroll
    for (int mf = 0; mf < 4; ++mf){
        int co0 = cot*64 + mf*16 + kg*4;
        float4 bv = *(const float4*)&bnb[co0];
        if (DOWN){
            float4 dv = *(const float4*)&dbb[co0];
            bv.x += dv.x; bv.y += dv.y; bv.z += dv.z; bv.w += dv.w;
        }
        #pragma unroll
        for (int nf = 0; nf < 2; ++nf){
            int px = ph*32 + nf*16 + ln;
            size_t o = (((size_t)(b0+bb)*64) + px)*512 + co0;
            f32x4 a = acc[mf][nf];
            float v0 = a[0] + bv.x, v1 = a[1] + bv.y;
            float v2 = a[2] + bv.z, v3 = a[3] + bv.w;
            if (RES){
                ushort4 rv = *(const ushort4*)&res[o];
                v0 += b2f(rv.x); v1 += b2f(rv.y); v2 += b2f(rv.z); v3 += b2f(rv.w);
            }
            ushort4 st;
            st.x = f2b(fmaxf(v0, 0.f)); st.y = f2b(fmaxf(v1, 0.f));
            st.z = f2b(fmaxf(v2, 0.f)); st.w = f2b(fmaxf(v3, 0.f));
            *(ushort4*)&out[o] = st;
        }
    }
}

// ---------------------------------------------------------------------------
// head: GAP(8x8) + linear 512->200 (unchanged).
// ---------------------------------------------------------------------------
__global__ __launch_bounds__(256)
void head_kernel(const u16* __restrict__ z, const float* __restrict__ hw,
                 float* __restrict__ pred)
{
    const int b = blockIdx.x, tid = threadIdx.x;
    __shared__ float feat[512];
    float s0 = 0.f, s1 = 0.f;
    for (int px = 0; px < 64; ++px){
        u32 u = *(const u32*)&z[(((size_t)b*64 + px)*512) + 2*tid];
        s0 += b2f((u16)(u & 0xFFFF));
        s1 += b2f((u16)(u >> 16));
    }
    feat[2*tid]   = s0 * (1.f/64.f);
    feat[2*tid+1] = s1 * (1.f/64.f);
    __syncthreads();
    if (tid < 200){
        float acc = 0.f;
        const float4* hp = (const float4*)&hw[(size_t)tid*512];
        #pragma unroll 8
        for (int i = 0; i < 128; ++i){
            float4 h = hp[i];
            float4 f = *(const float4*)&feat[i*4];
            acc += h.x*f.x + h.y*f.y + h.z*f.z + h.w*f.w;
        }
        pred[b*200 + tid] = acc;
    }
}

// ---------------------------------------------------------------------------
// gram: fused embed (emb LDS-resident) + Gram + sigmoid (unchanged).
// ---------------------------------------------------------------------------
__global__ __launch_bounds__(512, 2)
void gram_kernel(const float* __restrict__ x, const u16* __restrict__ wpe,
                 const float* __restrict__ eb, float* __restrict__ vol)
{
    const int b = blockIdx.x, tid = threadIdx.x;
    const int wid = tid >> 6, lane = tid & 63;
    const int ln = lane & 15, kg = lane >> 4;

    __shared__ u16 embl[256*136];        // 69,632 B
    __shared__ u16 xbl[256*40];          // 20,480 B
    __shared__ u16 ewl[128*40];          // 10,240 B

    f32x4 zero4 = {0.f,0.f,0.f,0.f};
    f32x4 ae[8][2];
    #pragma unroll
    for (int mf = 0; mf < 8; ++mf){ ae[mf][0] = zero4; ae[mf][1] = zero4; }

    for (int cc = 0; cc < 8; ++cc){
        __syncthreads();
        #pragma unroll
        for (int it = 0; it < 8; ++it){
            int f = it*512 + tid;
            int cip = f >> 8, px = f & 255;
            const float* src = &x[(((size_t)b*256 + cc*32 + 2*cip)*256) + px];
            *(u32*)&xbl[px*40 + 2*cip] = pack2(src[0], src[256]);
        }
        for (int j = tid; j < 640; j += 512)
            *(short8*)&ewl[j*8] = *(const short8*)&wpe[(cc*128)*40 + j*8];
        __syncthreads();
        short8 A[8];
        #pragma unroll
        for (int mf = 0; mf < 8; ++mf)
            A[mf] = *(const short8*)&ewl[(mf*16 + ln)*40 + kg*8];
        #pragma unroll
        for (int nf = 0; nf < 2; ++nf){
            short8 B = *(const short8*)&xbl[(wid*32 + nf*16 + ln)*40 + kg*8];
            #pragma unroll
            for (int mf = 0; mf < 8; ++mf)
                ae[mf][nf] = MFMA(A[mf], B, ae[mf][nf]);
        }
    }
    #pragma unroll
    for (int mf = 0; mf < 8; ++mf){
        int e0 = mf*16 + kg*4;
        float4 bv = *(const float4*)&eb[e0];
        #pragma unroll
        for (int nf = 0; nf < 2; ++nf){
            int px = wid*32 + nf*16 + ln;
            f32x4 a = ae[mf][nf];
            ushort4 st;
            st.x = f2b(a[0] + bv.x); st.y = f2b(a[1] + bv.y);
            st.z = f2b(a[2] + bv.z); st.w = f2b(a[3] + bv.w);
            *(ushort4*)&embl[px*136 + e0] = st;
        }
    }
    __syncthreads();

    const int wq = wid >> 2, wi = wid & 3;
    f32x4 g[8][4];
    #pragma unroll
    for (int mf = 0; mf < 8; ++mf)
        #pragma unroll
        for (int nf = 0; nf < 4; ++nf) g[mf][nf] = zero4;

    #pragma unroll
    for (int ks = 0; ks < 4; ++ks){
        short8 A[8];
        #pragma unroll
        for (int mf = 0; mf < 8; ++mf)
            A[mf] = *(const short8*)&embl[(wq*128 + mf*16 + ln)*136 + ks*32 + kg*8];
        #pragma unroll
        for (int nf = 0; nf < 4; ++nf){
            short8 B = *(const short8*)&embl[(wi*64 + nf*16 + ln)*136 + ks*32 + kg*8];
            #pragma unroll
            for (int mf = 0; mf < 8; ++mf)
                g[mf][nf] = MFMA(A[mf], B, g[mf][nf]);
        }
    }
    const float sc = 0.08838834764831845f;   // 1/sqrt(128)
    #pragma unroll
    for (int mf = 0; mf < 8; ++mf){
        #pragma unroll
        for (int nf = 0; nf < 4; ++nf){
            int i = wi*64 + nf*16 + ln;
            #pragma unroll
            for (int r = 0; r < 4; ++r){
                int q = wq*128 + mf*16 + kg*4 + r;
                vol[(((size_t)b*256 + q)*256) + i] = sigmoidf_(g[mf][nf][r] * sc);
            }
        }
    }
}

// ---------------------------------------------------------------------------
extern "C" void kernel_launch(void* const* d_in, const int* in_sizes, int n_in,
                              void* d_out, int out_size, void* d_ws, size_t ws_size,
                              hipStream_t stream)
{
    const float* x    = (const float*)d_in[0];
    const float* ew   = (const float*)d_in[1];
    const float* eb   = (const float*)d_in[2];
    const float* w1   = (const float*)d_in[3];
    const float* bn1s = (const float*)d_in[4];
    const float* bn1b = (const float*)d_in[5];
    const float* w2   = (const float*)d_in[6];
    const float* bn2s = (const float*)d_in[7];
    const float* bn2b = (const float*)d_in[8];
    const float* wd   = (const float*)d_in[9];
    const float* bnds = (const float*)d_in[10];
    const float* bndb = (const float*)d_in[11];
    const float* w3   = (const float*)d_in[12];
    const float* bn3s = (const float*)d_in[13];
    const float* bn3b = (const float*)d_in[14];
    const float* w4   = (const float*)d_in[15];
    const float* bn4s = (const float*)d_in[16];
    const float* bn4b = (const float*)d_in[17];
    const float* hw   = (const float*)d_in[18];

    float* pred = (float*)d_out;            // [256,200]
    float* vol  = pred + 51200;             // [256,256,256] f32

    u16* wp2 = (u16*)d_ws;
    u16* wp3 = wp2 + 2949120;
    u16* wp4 = wp3 + 2949120;
    u16* wp1 = wp4 + 2949120;
    u16* wpd = wp1 + 1474560;
    u16* wpe = wpd + 163840;

    u16* y1 = (u16*)vol;
    u16* y  = y1 + 8388608;
    u16* z1 = y  + 8388608;
    u16* z  = z1 + 8388608;

    prep_kernel<<<41120, 256, 0, stream>>>(w1, bn1s, w2, bn2s, w3, bn3s, w4, bn4s,
                                           wd, bnds, ew, wp1, wp2, wp3, wp4, wpd, wpe);
    conv1_kernel<<<dim3(2,128), 512, 0, stream>>>(x, wp1, bn1b, y1);
    conv_s1_kernel<1,0><<<dim3(128,8), 256, 0, stream>>>(y1, wp2, bn2b, x, wpd, bndb,
                                                         nullptr, y);
    conv_s1_kernel<0,0><<<dim3(128,8), 256, 0, stream>>>(y, wp3, bn3b, nullptr, nullptr,
                                                         nullptr, nullptr, z1);
    conv_s1_kernel<0,1><<<dim3(128,8), 256, 0, stream>>>(z1, wp4, bn4b, nullptr, nullptr,
                                                         nullptr, y, z);
    head_kernel<<<256, 256, 0, stream>>>(z, hw, pred);
    gram_kernel<<<256, 512, 0, stream>>>(x, wpe, eb, vol);
}

// Round 5
// 426.816 us; speedup vs baseline: 25.8426x; 1.0512x over previous
//
#include <hip/hip_runtime.h>

// ---------------------------------------------------------------------------
// SelfConsistNet, bf16 MFMA implicit-GEMM pipeline (NHWC activations), r5.
// Changes vs r4 (conv_s1 only):
//  - per-wave output tile 64co x 64px (nf=4): per-wave A-panel (590KB) now
//    serves 2x the outputs -> total A VMEM 2.4GB -> 1.2GB (the measured
//    dominant term). Block = 128thr/2 waves, M=128co, N=64px (1 batch).
//  - grid (b=256, cot=4) -> XCD = b%8; per-XCD act slice 2MB + lockstep
//    weight window ~600KB fits L2.
//  - __launch_bounds__(128,3): ~170 VGPR budget so acc(64)+A-preload(48)
//    stay in registers (r4's 64-VGPR squeeze serialized the A pipeline).
//  - dropped XOR swizzle (80B row stride is already a 32-bank partition).
// ---------------------------------------------------------------------------

using short8 = __attribute__((ext_vector_type(8))) short;   // 8 bf16 (4 VGPR)
using f32x4  = __attribute__((ext_vector_type(4))) float;   // MFMA acc
typedef unsigned short u16;
typedef unsigned int   u32;

#define MFMA(a,b,c) __builtin_amdgcn_mfma_f32_16x16x32_bf16((a),(b),(c),0,0,0)

__device__ __forceinline__ u16 f2b(float f){
    u32 u = __builtin_bit_cast(u32, f);
    u += 0x7FFFu + ((u >> 16) & 1u);        // RNE
    return (u16)(u >> 16);
}
__device__ __forceinline__ float b2f(u16 h){
    u32 u = ((u32)h) << 16;
    return __builtin_bit_cast(float, u);
}
__device__ __forceinline__ u32 pack2(float a, float b){
    return (u32)f2b(a) | ((u32)f2b(b) << 16);
}
__device__ __forceinline__ float sigmoidf_(float v){
    return 1.0f / (1.0f + __expf(-v));
}

// ---------------------------------------------------------------------------
// Weight prep (unchanged): bf16 [dydx][cc][co][40] fragment tiles, BN folded.
// ---------------------------------------------------------------------------
__global__ __launch_bounds__(256)
void prep_kernel(const float* __restrict__ w1, const float* __restrict__ s1,
                 const float* __restrict__ w2, const float* __restrict__ s2,
                 const float* __restrict__ w3, const float* __restrict__ s3,
                 const float* __restrict__ w4, const float* __restrict__ s4,
                 const float* __restrict__ wd, const float* __restrict__ sd,
                 const float* __restrict__ ew,
                 u16* __restrict__ wp1, u16* __restrict__ wp2,
                 u16* __restrict__ wp3, u16* __restrict__ wp4,
                 u16* __restrict__ wpd, u16* __restrict__ wpe)
{
    const int N2 = 9*16*512*40, N1 = 9*8*512*40, ND = 8*512*40, NE = 8*128*40;
    int t = blockIdx.x * 256 + threadIdx.x;
    if (t < N2) {
        int j = t % 40; int r = t / 40; int co = r & 511; int q = r >> 9;
        int cc = q & 15; int dydx = q >> 4;
        float v = (j < 32) ? w2[(co*512 + cc*32 + j)*9 + dydx] * s2[co] : 0.f;
        wp2[t] = f2b(v); return;
    }
    t -= N2;
    if (t < N2) {
        int j = t % 40; int r = t / 40; int co = r & 511; int q = r >> 9;
        int cc = q & 15; int dydx = q >> 4;
        float v = (j < 32) ? w3[(co*512 + cc*32 + j)*9 + dydx] * s3[co] : 0.f;
        wp3[t] = f2b(v); return;
    }
    t -= N2;
    if (t < N2) {
        int j = t % 40; int r = t / 40; int co = r & 511; int q = r >> 9;
        int cc = q & 15; int dydx = q >> 4;
        float v = (j < 32) ? w4[(co*512 + cc*32 + j)*9 + dydx] * s4[co] : 0.f;
        wp4[t] = f2b(v); return;
    }
    t -= N2;
    if (t < N1) {
        int j = t % 40; int r = t / 40; int co = r & 511; int q = r >> 9;
        int cc = q & 7; int dydx = q >> 3;
        float v = (j < 32) ? w1[(co*256 + cc*32 + j)*9 + dydx] * s1[co] : 0.f;
        wp1[t] = f2b(v); return;
    }
    t -= N1;
    if (t < ND) {
        int j = t % 40; int r = t / 40; int co = r & 511; int cc = r >> 9;
        float v = (j < 32) ? wd[co*256 + cc*32 + j] * sd[co] : 0.f;
        wpd[t] = f2b(v); return;
    }
    t -= ND;
    if (t < NE) {
        int j = t % 40; int r = t / 40; int e = r & 127; int cc = r >> 7;
        float v = (j < 32) ? ew[e*256 + cc*32 + j] : 0.f;
        wpe[t] = f2b(v);
    }
}

// ---------------------------------------------------------------------------
// K1: conv3x3 s2 (unchanged from r3/r4).
// ---------------------------------------------------------------------------
__global__ __launch_bounds__(512, 2)
void conv1_kernel(const float* __restrict__ x, const u16* __restrict__ wp,
                  const float* __restrict__ bnb, u16* __restrict__ out)
{
    const int cot = blockIdx.x;          // 0..1
    const int b0  = blockIdx.y * 2;
    const int tid = threadIdx.x;
    const int wid = tid >> 6, lane = tid & 63;
    const int ln = lane & 15, kg = lane >> 4;
    const int wco = wid >> 1;            // 0..3
    const int bb  = wid & 1;             // 0..1

    __shared__ u16 actb[2][2*289*40];    // 92,480 B

    {
        short8 zz = {0,0,0,0,0,0,0,0};
        short8* ab = (short8*)&actb[0][0];
        for (int j = tid; j < 2*2*289*40/8; j += 512) ab[j] = zz;
    }
    __syncthreads();

    auto stage_act = [&](int cc, int p){
        #pragma unroll
        for (int it = 0; it < 16; ++it){
            int f = it*512 + tid;                    // 8192 dwords
            int bb2 = f >> 12; int rem = f & 4095;
            int cip = rem >> 8; int px = rem & 255;
            const float* src = &x[(((size_t)(b0+bb2)*256 + cc*32 + 2*cip)*256) + px];
            float v0 = src[0], v1 = src[256];
            int r = ((px >> 4) + 1)*17 + (px & 15) + 1;
            *(u32*)&actb[p][(bb2*289 + r)*40 + 2*cip] = pack2(v0, v1);
        }
    };

    stage_act(0, 0);
    __syncthreads();

    f32x4 zero4 = {0.f,0.f,0.f,0.f};
    f32x4 acc[4][4];
    #pragma unroll
    for (int mf = 0; mf < 4; ++mf)
        #pragma unroll
        for (int nf = 0; nf < 4; ++nf) acc[mf][nf] = zero4;

    int bbase[4];
    #pragma unroll
    for (int nf = 0; nf < 4; ++nf){
        int px = nf*16 + ln;
        bbase[nf] = (bb*289 + 34*(px>>3) + 2*(px&7))*40 + kg*8;
    }

    for (int cc = 0; cc < 8; ++cc){
        if (cc < 7) stage_act(cc+1, (cc+1) & 1);
        const u16* abp = actb[cc & 1];
        #pragma unroll
        for (int d = 0; d < 9; ++d){
            const u16* wdp = wp + ((size_t)(d*8 + cc)*512 + cot*256)*40;
            int dy = d/3, dx = d - dy*3;
            int shift = (dy*17 + dx)*40;
            short8 A[4];
            #pragma unroll
            for (int mf = 0; mf < 4; ++mf)
                A[mf] = *(const short8*)&wdp[(wco*64 + mf*16 + ln)*40 + kg*8];
            #pragma unroll
            for (int nf = 0; nf < 4; ++nf){
                short8 B = *(const short8*)&abp[bbase[nf] + shift];
                #pragma unroll
                for (int mf = 0; mf < 4; ++mf)
                    acc[mf][nf] = MFMA(A[mf], B, acc[mf][nf]);
            }
        }
        __syncthreads();
    }

    #pragma unroll
    for (int mf = 0; mf < 4; ++mf){
        int co0 = cot*256 + wco*64 + mf*16 + kg*4;
        float4 bv = *(const float4*)&bnb[co0];
        #pragma unroll
        for (int nf = 0; nf < 4; ++nf){
            int px = nf*16 + ln;
            size_t o = (((size_t)(b0+bb)*64) + px)*512 + co0;
            f32x4 a = acc[mf][nf];
            ushort4 st;
            st.x = f2b(fmaxf(a[0] + bv.x, 0.f));
            st.y = f2b(fmaxf(a[1] + bv.y, 0.f));
            st.z = f2b(fmaxf(a[2] + bv.z, 0.f));
            st.w = f2b(fmaxf(a[3] + bv.w, 0.f));
            *(ushort4*)&out[o] = st;
        }
    }
}

// ---------------------------------------------------------------------------
// K2/K3/K4 (r5): 128 thr = 2 waves (wco 0..1); wave tile 64co x 64px.
// Block = 128co x 64px (1 batch). grid (b=256, cot=4) -> XCD = b%8.
// act LDS dbuf 16,000 B; A-frags direct from global, 12-deep preload per dy.
// 16 barriers (1/cc). acc[4][4]=64 VGPR, launch_bounds(128,3) -> ~170 cap.
// ---------------------------------------------------------------------------
template<int DOWN, int RES>
__global__ __launch_bounds__(128, 3)
void conv_s1_kernel(const u16* __restrict__ in, const u16* __restrict__ wp,
                    const float* __restrict__ bnb,
                    const float* __restrict__ x, const u16* __restrict__ wpd,
                    const float* __restrict__ dbb,
                    const u16* __restrict__ res, u16* __restrict__ out)
{
    const int b   = blockIdx.x;          // 0..255 (XCD = b%8)
    const int cot = blockIdx.y;          // 0..3 (128 co)
    const int tid = threadIdx.x;
    const int wid = tid >> 6;            // wco 0..1
    const int lane = tid & 63;
    const int ln = lane & 15, kg = lane >> 4;

    __shared__ u16 actb[2][100*40];      // 16,000 B

    {
        short8 zz = {0,0,0,0,0,0,0,0};
        short8* ab = (short8*)&actb[0][0];
        for (int j = tid; j < 2*100*40/8; j += 128) ab[j] = zz;
    }
    __syncthreads();

    // staging: 256 short8 per cc-chunk, 2 per thread
    const int j0 = tid, j1 = 128 + tid;
    const int px0 = j0 >> 2, cg0 = j0 & 3;
    const int px1 = j1 >> 2, cg1 = j1 & 3;
    const int ld0 = (((px0>>3)+1)*10 + (px0&7) + 1)*40 + cg0*8;
    const int ld1 = (((px1>>3)+1)*10 + (px1&7) + 1)*40 + cg1*8;

    short8 sreg0, sreg1;
    auto stage_load = [&](int cc){
        sreg0 = *(const short8*)&in[(((size_t)b*64 + px0)*512) + cc*32 + cg0*8];
        sreg1 = *(const short8*)&in[(((size_t)b*64 + px1)*512) + cc*32 + cg1*8];
    };
    auto stage_store = [&](int p){
        *(short8*)&actb[p][ld0] = sreg0;
        *(short8*)&actb[p][ld1] = sreg1;
    };

    stage_load(0); stage_store(0);
    __syncthreads();

    f32x4 zero4 = {0.f,0.f,0.f,0.f};
    f32x4 acc[4][4];
    #pragma unroll
    for (int mf = 0; mf < 4; ++mf)
        #pragma unroll
        for (int nf = 0; nf < 4; ++nf) acc[mf][nf] = zero4;

    int bro[4];
    #pragma unroll
    for (int nf = 0; nf < 4; ++nf){
        int px = nf*16 + ln;
        bro[nf] = ((px>>3)*10 + (px&7))*40 + kg*8;
    }
    const int aoff = ln*40 + kg*8;
    const int abase = (cot*128 + wid*64)*40;

    for (int cc = 0; cc < 16; ++cc){
        if (cc < 15) stage_load(cc+1);
        const u16* abp = actb[cc & 1];
        #pragma unroll
        for (int dy = 0; dy < 3; ++dy){
            // preload all 12 A-fragments for this dy (3 dx x 4 mf)
            short8 A[3][4];
            #pragma unroll
            for (int dx = 0; dx < 3; ++dx){
                const u16* wdp = wp + (size_t)((dy*3+dx)*16 + cc)*512*40 + abase;
                #pragma unroll
                for (int mf = 0; mf < 4; ++mf)
                    A[dx][mf] = *(const short8*)&wdp[mf*640 + aoff];
            }
            #pragma unroll
            for (int dx = 0; dx < 3; ++dx){
                int shift = (dy*10 + dx)*40;
                #pragma unroll
                for (int nf = 0; nf < 4; ++nf){
                    short8 B = *(const short8*)&abp[bro[nf] + shift];
                    #pragma unroll
                    for (int mf = 0; mf < 4; ++mf)
                        acc[mf][nf] = MFMA(A[dx][mf], B, acc[mf][nf]);
                }
            }
        }
        if (cc < 15){
            stage_store((cc+1) & 1);
            __syncthreads();
        }
    }

    if (DOWN){
        // fused 1x1 stride-2 downsample from x (NCHW f32), K=256 in 8 chunks
        for (int dc = 0; dc < 8; ++dc){
            __syncthreads();
            #pragma unroll
            for (int it = 0; it < 8; ++it){
                int f = it*128 + tid;                // 1024 dword-pairs
                int cip = f >> 6, px2 = f & 63;
                int ipx = (px2>>3)*32 + (px2&7)*2;
                const float* src = &x[(((size_t)b*256 + dc*32 + 2*cip)*256) + ipx];
                *(u32*)&actb[0][px2*40 + cip*2] = pack2(src[0], src[256]);
            }
            __syncthreads();
            const u16* wdp = wpd + (size_t)(dc*512)*40 + abase;
            short8 A[4];
            #pragma unroll
            for (int mf = 0; mf < 4; ++mf)
                A[mf] = *(const short8*)&wdp[mf*640 + aoff];
            #pragma unroll
            for (int nf = 0; nf < 4; ++nf){
                int rd = nf*16 + ln;
                short8 B = *(const short8*)&actb[0][rd*40 + kg*8];
                #pragma unroll
                for (int mf = 0; mf < 4; ++mf)
                    acc[mf][nf] = MFMA(A[mf], B, acc[mf][nf]);
            }
        }
    }

    #pragma unroll
    for (int mf = 0; mf < 4; ++mf){
        int co0 = cot*128 + wid*64 + mf*16 + kg*4;
        float4 bv = *(const float4*)&bnb[co0];
        if (DOWN){
            float4 dv = *(const float4*)&dbb[co0];
            bv.x += dv.x; bv.y += dv.y; bv.z += dv.z; bv.w += dv.w;
        }
        #pragma unroll
        for (int nf = 0; nf < 4; ++nf){
            int px = nf*16 + ln;
            size_t o = (((size_t)b*64) + px)*512 + co0;
            f32x4 a = acc[mf][nf];
            float v0 = a[0] + bv.x, v1 = a[1] + bv.y;
            float v2 = a[2] + bv.z, v3 = a[3] + bv.w;
            if (RES){
                ushort4 rv = *(const ushort4*)&res[o];
                v0 += b2f(rv.x); v1 += b2f(rv.y); v2 += b2f(rv.z); v3 += b2f(rv.w);
            }
            ushort4 st;
            st.x = f2b(fmaxf(v0, 0.f)); st.y = f2b(fmaxf(v1, 0.f));
            st.z = f2b(fmaxf(v2, 0.f)); st.w = f2b(fmaxf(v3, 0.f));
            *(ushort4*)&out[o] = st;
        }
    }
}

// ---------------------------------------------------------------------------
// head: GAP(8x8) + linear 512->200 (unchanged).
// ---------------------------------------------------------------------------
__global__ __launch_bounds__(256)
void head_kernel(const u16* __restrict__ z, const float* __restrict__ hw,
                 float* __restrict__ pred)
{
    const int b = blockIdx.x, tid = threadIdx.x;
    __shared__ float feat[512];
    float s0 = 0.f, s1 = 0.f;
    for (int px = 0; px < 64; ++px){
        u32 u = *(const u32*)&z[(((size_t)b*64 + px)*512) + 2*tid];
        s0 += b2f((u16)(u & 0xFFFF));
        s1 += b2f((u16)(u >> 16));
    }
    feat[2*tid]   = s0 * (1.f/64.f);
    feat[2*tid+1] = s1 * (1.f/64.f);
    __syncthreads();
    if (tid < 200){
        float acc = 0.f;
        const float4* hp = (const float4*)&hw[(size_t)tid*512];
        #pragma unroll 8
        for (int i = 0; i < 128; ++i){
            float4 h = hp[i];
            float4 f = *(const float4*)&feat[i*4];
            acc += h.x*f.x + h.y*f.y + h.z*f.z + h.w*f.w;
        }
        pred[b*200 + tid] = acc;
    }
}

// ---------------------------------------------------------------------------
// gram: fused embed (emb LDS-resident) + Gram + sigmoid (unchanged).
// ---------------------------------------------------------------------------
__global__ __launch_bounds__(512, 2)
void gram_kernel(const float* __restrict__ x, const u16* __restrict__ wpe,
                 const float* __restrict__ eb, float* __restrict__ vol)
{
    const int b = blockIdx.x, tid = threadIdx.x;
    const int wid = tid >> 6, lane = tid & 63;
    const int ln = lane & 15, kg = lane >> 4;

    __shared__ u16 embl[256*136];        // 69,632 B
    __shared__ u16 xbl[256*40];          // 20,480 B
    __shared__ u16 ewl[128*40];          // 10,240 B

    f32x4 zero4 = {0.f,0.f,0.f,0.f};
    f32x4 ae[8][2];
    #pragma unroll
    for (int mf = 0; mf < 8; ++mf){ ae[mf][0] = zero4; ae[mf][1] = zero4; }

    for (int cc = 0; cc < 8; ++cc){
        __syncthreads();
        #pragma unroll
        for (int it = 0; it < 8; ++it){
            int f = it*512 + tid;
            int cip = f >> 8, px = f & 255;
            const float* src = &x[(((size_t)b*256 + cc*32 + 2*cip)*256) + px];
            *(u32*)&xbl[px*40 + 2*cip] = pack2(src[0], src[256]);
        }
        for (int j = tid; j < 640; j += 512)
            *(short8*)&ewl[j*8] = *(const short8*)&wpe[(cc*128)*40 + j*8];
        __syncthreads();
        short8 A[8];
        #pragma unroll
        for (int mf = 0; mf < 8; ++mf)
            A[mf] = *(const short8*)&ewl[(mf*16 + ln)*40 + kg*8];
        #pragma unroll
        for (int nf = 0; nf < 2; ++nf){
            short8 B = *(const short8*)&xbl[(wid*32 + nf*16 + ln)*40 + kg*8];
            #pragma unroll
            for (int mf = 0; mf < 8; ++mf)
                ae[mf][nf] = MFMA(A[mf], B, ae[mf][nf]);
        }
    }
    #pragma unroll
    for (int mf = 0; mf < 8; ++mf){
        int e0 = mf*16 + kg*4;
        float4 bv = *(const float4*)&eb[e0];
        #pragma unroll
        for (int nf = 0; nf < 2; ++nf){
            int px = wid*32 + nf*16 + ln;
            f32x4 a = ae[mf][nf];
            ushort4 st;
            st.x = f2b(a[0] + bv.x); st.y = f2b(a[1] + bv.y);
            st.z = f2b(a[2] + bv.z); st.w = f2b(a[3] + bv.w);
            *(ushort4*)&embl[px*136 + e0] = st;
        }
    }
    __syncthreads();

    const int wq = wid >> 2, wi = wid & 3;
    f32x4 g[8][4];
    #pragma unroll
    for (int mf = 0; mf < 8; ++mf)
        #pragma unroll
        for (int nf = 0; nf < 4; ++nf) g[mf][nf] = zero4;

    #pragma unroll
    for (int ks = 0; ks < 4; ++ks){
        short8 A[8];
        #pragma unroll
        for (int mf = 0; mf < 8; ++mf)
            A[mf] = *(const short8*)&embl[(wq*128 + mf*16 + ln)*136 + ks*32 + kg*8];
        #pragma unroll
        for (int nf = 0; nf < 4; ++nf){
            short8 B = *(const short8*)&embl[(wi*64 + nf*16 + ln)*136 + ks*32 + kg*8];
            #pragma unroll
            for (int mf = 0; mf < 8; ++mf)
                g[mf][nf] = MFMA(A[mf], B, g[mf][nf]);
        }
    }
    const float sc = 0.08838834764831845f;   // 1/sqrt(128)
    #pragma unroll
    for (int mf = 0; mf < 8; ++mf){
        #pragma unroll
        for (int nf = 0; nf < 4; ++nf){
            int i = wi*64 + nf*16 + ln;
            #pragma unroll
            for (int r = 0; r < 4; ++r){
                int q = wq*128 + mf*16 + kg*4 + r;
                vol[(((size_t)b*256 + q)*256) + i] = sigmoidf_(g[mf][nf][r] * sc);
            }
        }
    }
}

// ---------------------------------------------------------------------------
extern "C" void kernel_launch(void* const* d_in, const int* in_sizes, int n_in,
                              void* d_out, int out_size, void* d_ws, size_t ws_size,
                              hipStream_t stream)
{
    const float* x    = (const float*)d_in[0];
    const float* ew   = (const float*)d_in[1];
    const float* eb   = (const float*)d_in[2];
    const float* w1   = (const float*)d_in[3];
    const float* bn1s = (const float*)d_in[4];
    const float* bn1b = (const float*)d_in[5];
    const float* w2   = (const float*)d_in[6];
    const float* bn2s = (const float*)d_in[7];
    const float* bn2b = (const float*)d_in[8];
    const float* wd   = (const float*)d_in[9];
    const float* bnds = (const float*)d_in[10];
    const float* bndb = (const float*)d_in[11];
    const float* w3   = (const float*)d_in[12];
    const float* bn3s = (const float*)d_in[13];
    const float* bn3b = (const float*)d_in[14];
    const float* w4   = (const float*)d_in[15];
    const float* bn4s = (const float*)d_in[16];
    const float* bn4b = (const float*)d_in[17];
    const float* hw   = (const float*)d_in[18];

    float* pred = (float*)d_out;            // [256,200]
    float* vol  = pred + 51200;             // [256,256,256] f32

    u16* wp2 = (u16*)d_ws;
    u16* wp3 = wp2 + 2949120;
    u16* wp4 = wp3 + 2949120;
    u16* wp1 = wp4 + 2949120;
    u16* wpd = wp1 + 1474560;
    u16* wpe = wpd + 163840;

    u16* y1 = (u16*)vol;
    u16* y  = y1 + 8388608;
    u16* z1 = y  + 8388608;
    u16* z  = z1 + 8388608;

    prep_kernel<<<41120, 256, 0, stream>>>(w1, bn1s, w2, bn2s, w3, bn3s, w4, bn4s,
                                           wd, bnds, ew, wp1, wp2, wp3, wp4, wpd, wpe);
    conv1_kernel<<<dim3(2,128), 512, 0, stream>>>(x, wp1, bn1b, y1);
    conv_s1_kernel<1,0><<<dim3(256,4), 128, 0, stream>>>(y1, wp2, bn2b, x, wpd, bndb,
                                                         nullptr, y);
    conv_s1_kernel<0,0><<<dim3(256,4), 128, 0, stream>>>(y, wp3, bn3b, nullptr, nullptr,
                                                         nullptr, nullptr, z1);
    conv_s1_kernel<0,1><<<dim3(256,4), 128, 0, stream>>>(z1, wp4, bn4b, nullptr, nullptr,
                                                         nullptr, y, z);
    head_kernel<<<256, 256, 0, stream>>>(z, hw, pred);
    gram_kernel<<<256, 512, 0, stream>>>(x, wpe, eb, vol);
}

// Round 6
// 400.427 us; speedup vs baseline: 27.5456x; 1.0659x over previous
//
#include <hip/hip_runtime.h>

// ---------------------------------------------------------------------------
// SelfConsistNet, bf16 MFMA implicit-GEMM pipeline (NHWC activations), r6.
// Changes vs r5 (conv_s1 only):
//  - SINGLE-WAVE blocks (64 thr), wave tile 64co x 64px, grid (256 b, 8 cot)
//    = 2048 blocks = 8 blocks/CU. Zero __syncthreads in the hot loop: a
//    single wave orders LDS dbuf + staging purely via lgkmcnt/vmcnt, so
//    each wave is self-paced (no barrier convoy, no sibling stalls).
//  - LDS 16KB/block (8x16=128KB/CU ok); launch_bounds(64,2) -> full VGPR
//    budget for acc(64)+A-preload(48)+staging regs.
//  - XCD = (b + 256*cot)%8 = b%8: act partition preserved (65MB FETCH kept).
// ---------------------------------------------------------------------------

using short8 = __attribute__((ext_vector_type(8))) short;   // 8 bf16 (4 VGPR)
using f32x4  = __attribute__((ext_vector_type(4))) float;   // MFMA acc
typedef unsigned short u16;
typedef unsigned int   u32;

#define MFMA(a,b,c) __builtin_amdgcn_mfma_f32_16x16x32_bf16((a),(b),(c),0,0,0)

__device__ __forceinline__ u16 f2b(float f){
    u32 u = __builtin_bit_cast(u32, f);
    u += 0x7FFFu + ((u >> 16) & 1u);        // RNE
    return (u16)(u >> 16);
}
__device__ __forceinline__ float b2f(u16 h){
    u32 u = ((u32)h) << 16;
    return __builtin_bit_cast(float, u);
}
__device__ __forceinline__ u32 pack2(float a, float b){
    return (u32)f2b(a) | ((u32)f2b(b) << 16);
}
__device__ __forceinline__ float sigmoidf_(float v){
    return 1.0f / (1.0f + __expf(-v));
}

// ---------------------------------------------------------------------------
// Weight prep (unchanged): bf16 [dydx][cc][co][40] fragment tiles, BN folded.
// ---------------------------------------------------------------------------
__global__ __launch_bounds__(256)
void prep_kernel(const float* __restrict__ w1, const float* __restrict__ s1,
                 const float* __restrict__ w2, const float* __restrict__ s2,
                 const float* __restrict__ w3, const float* __restrict__ s3,
                 const float* __restrict__ w4, const float* __restrict__ s4,
                 const float* __restrict__ wd, const float* __restrict__ sd,
                 const float* __restrict__ ew,
                 u16* __restrict__ wp1, u16* __restrict__ wp2,
                 u16* __restrict__ wp3, u16* __restrict__ wp4,
                 u16* __restrict__ wpd, u16* __restrict__ wpe)
{
    const int N2 = 9*16*512*40, N1 = 9*8*512*40, ND = 8*512*40, NE = 8*128*40;
    int t = blockIdx.x * 256 + threadIdx.x;
    if (t < N2) {
        int j = t % 40; int r = t / 40; int co = r & 511; int q = r >> 9;
        int cc = q & 15; int dydx = q >> 4;
        float v = (j < 32) ? w2[(co*512 + cc*32 + j)*9 + dydx] * s2[co] : 0.f;
        wp2[t] = f2b(v); return;
    }
    t -= N2;
    if (t < N2) {
        int j = t % 40; int r = t / 40; int co = r & 511; int q = r >> 9;
        int cc = q & 15; int dydx = q >> 4;
        float v = (j < 32) ? w3[(co*512 + cc*32 + j)*9 + dydx] * s3[co] : 0.f;
        wp3[t] = f2b(v); return;
    }
    t -= N2;
    if (t < N2) {
        int j = t % 40; int r = t / 40; int co = r & 511; int q = r >> 9;
        int cc = q & 15; int dydx = q >> 4;
        float v = (j < 32) ? w4[(co*512 + cc*32 + j)*9 + dydx] * s4[co] : 0.f;
        wp4[t] = f2b(v); return;
    }
    t -= N2;
    if (t < N1) {
        int j = t % 40; int r = t / 40; int co = r & 511; int q = r >> 9;
        int cc = q & 7; int dydx = q >> 3;
        float v = (j < 32) ? w1[(co*256 + cc*32 + j)*9 + dydx] * s1[co] : 0.f;
        wp1[t] = f2b(v); return;
    }
    t -= N1;
    if (t < ND) {
        int j = t % 40; int r = t / 40; int co = r & 511; int cc = r >> 9;
        float v = (j < 32) ? wd[co*256 + cc*32 + j] * sd[co] : 0.f;
        wpd[t] = f2b(v); return;
    }
    t -= ND;
    if (t < NE) {
        int j = t % 40; int r = t / 40; int e = r & 127; int cc = r >> 7;
        float v = (j < 32) ? ew[e*256 + cc*32 + j] : 0.f;
        wpe[t] = f2b(v);
    }
}

// ---------------------------------------------------------------------------
// K1: conv3x3 s2 (unchanged from r3/r4/r5).
// ---------------------------------------------------------------------------
__global__ __launch_bounds__(512, 2)
void conv1_kernel(const float* __restrict__ x, const u16* __restrict__ wp,
                  const float* __restrict__ bnb, u16* __restrict__ out)
{
    const int cot = blockIdx.x;          // 0..1
    const int b0  = blockIdx.y * 2;
    const int tid = threadIdx.x;
    const int wid = tid >> 6, lane = tid & 63;
    const int ln = lane & 15, kg = lane >> 4;
    const int wco = wid >> 1;            // 0..3
    const int bb  = wid & 1;             // 0..1

    __shared__ u16 actb[2][2*289*40];    // 92,480 B

    {
        short8 zz = {0,0,0,0,0,0,0,0};
        short8* ab = (short8*)&actb[0][0];
        for (int j = tid; j < 2*2*289*40/8; j += 512) ab[j] = zz;
    }
    __syncthreads();

    auto stage_act = [&](int cc, int p){
        #pragma unroll
        for (int it = 0; it < 16; ++it){
            int f = it*512 + tid;                    // 8192 dwords
            int bb2 = f >> 12; int rem = f & 4095;
            int cip = rem >> 8; int px = rem & 255;
            const float* src = &x[(((size_t)(b0+bb2)*256 + cc*32 + 2*cip)*256) + px];
            float v0 = src[0], v1 = src[256];
            int r = ((px >> 4) + 1)*17 + (px & 15) + 1;
            *(u32*)&actb[p][(bb2*289 + r)*40 + 2*cip] = pack2(v0, v1);
        }
    };

    stage_act(0, 0);
    __syncthreads();

    f32x4 zero4 = {0.f,0.f,0.f,0.f};
    f32x4 acc[4][4];
    #pragma unroll
    for (int mf = 0; mf < 4; ++mf)
        #pragma unroll
        for (int nf = 0; nf < 4; ++nf) acc[mf][nf] = zero4;

    int bbase[4];
    #pragma unroll
    for (int nf = 0; nf < 4; ++nf){
        int px = nf*16 + ln;
        bbase[nf] = (bb*289 + 34*(px>>3) + 2*(px&7))*40 + kg*8;
    }

    for (int cc = 0; cc < 8; ++cc){
        if (cc < 7) stage_act(cc+1, (cc+1) & 1);
        const u16* abp = actb[cc & 1];
        #pragma unroll
        for (int d = 0; d < 9; ++d){
            const u16* wdp = wp + ((size_t)(d*8 + cc)*512 + cot*256)*40;
            int dy = d/3, dx = d - dy*3;
            int shift = (dy*17 + dx)*40;
            short8 A[4];
            #pragma unroll
            for (int mf = 0; mf < 4; ++mf)
                A[mf] = *(const short8*)&wdp[(wco*64 + mf*16 + ln)*40 + kg*8];
            #pragma unroll
            for (int nf = 0; nf < 4; ++nf){
                short8 B = *(const short8*)&abp[bbase[nf] + shift];
                #pragma unroll
                for (int mf = 0; mf < 4; ++mf)
                    acc[mf][nf] = MFMA(A[mf], B, acc[mf][nf]);
            }
        }
        __syncthreads();
    }

    #pragma unroll
    for (int mf = 0; mf < 4; ++mf){
        int co0 = cot*256 + wco*64 + mf*16 + kg*4;
        float4 bv = *(const float4*)&bnb[co0];
        #pragma unroll
        for (int nf = 0; nf < 4; ++nf){
            int px = nf*16 + ln;
            size_t o = (((size_t)(b0+bb)*64) + px)*512 + co0;
            f32x4 a = acc[mf][nf];
            ushort4 st;
            st.x = f2b(fmaxf(a[0] + bv.x, 0.f));
            st.y = f2b(fmaxf(a[1] + bv.y, 0.f));
            st.z = f2b(fmaxf(a[2] + bv.z, 0.f));
            st.w = f2b(fmaxf(a[3] + bv.w, 0.f));
            *(ushort4*)&out[o] = st;
        }
    }
}

// ---------------------------------------------------------------------------
// K2/K3/K4 (r6): SINGLE-WAVE blocks. 64 thr, wave tile 64co x 64px (1 batch).
// grid (b=256, cot=8) -> XCD = b%8. act LDS dbuf 16,000 B per block.
// No __syncthreads anywhere in the loop: lgkmcnt/vmcnt order everything.
// A-frags direct from global, 12-deep preload per dy.
// ---------------------------------------------------------------------------
template<int DOWN, int RES>
__global__ __launch_bounds__(64, 2)
void conv_s1_kernel(const u16* __restrict__ in, const u16* __restrict__ wp,
                    const float* __restrict__ bnb,
                    const float* __restrict__ x, const u16* __restrict__ wpd,
                    const float* __restrict__ dbb,
                    const u16* __restrict__ res, u16* __restrict__ out)
{
    const int b   = blockIdx.x;          // 0..255 (XCD = b%8)
    const int cot = blockIdx.y;          // 0..7 (64 co)
    const int lane = threadIdx.x;        // 0..63, single wave
    const int ln = lane & 15, kg = lane >> 4;

    __shared__ u16 actb[2][100*40];      // 16,000 B

    {
        short8 zz = {0,0,0,0,0,0,0,0};
        short8* ab = (short8*)&actb[0][0];
        #pragma unroll
        for (int it = 0; it < 16; ++it){
            int j = it*64 + lane;
            if (j < 1000) ab[j] = zz;
        }
    }

    // staging: 256 short8 per cc-chunk, 4 per lane
    int s_ld[4]; size_t s_go[4];
    #pragma unroll
    for (int it = 0; it < 4; ++it){
        int j = it*64 + lane;
        int px = j >> 2, cg = j & 3;
        s_ld[it] = (((px>>3)+1)*10 + (px&7) + 1)*40 + cg*8;
        s_go[it] = (((size_t)b*64 + px)*512) + cg*8;
    }

    short8 sreg[4];
    auto stage_load = [&](int cc){
        #pragma unroll
        for (int it = 0; it < 4; ++it)
            sreg[it] = *(const short8*)&in[s_go[it] + cc*32];
    };
    auto stage_store = [&](int p){
        #pragma unroll
        for (int it = 0; it < 4; ++it)
            *(short8*)&actb[p][s_ld[it]] = sreg[it];
    };

    stage_load(0); stage_store(0);

    f32x4 zero4 = {0.f,0.f,0.f,0.f};
    f32x4 acc[4][4];
    #pragma unroll
    for (int mf = 0; mf < 4; ++mf)
        #pragma unroll
        for (int nf = 0; nf < 4; ++nf) acc[mf][nf] = zero4;

    int bro[4];
    #pragma unroll
    for (int nf = 0; nf < 4; ++nf){
        int px = nf*16 + ln;
        bro[nf] = ((px>>3)*10 + (px&7))*40 + kg*8;
    }
    const int aoff = ln*40 + kg*8;
    const int abase = cot*64*40;

    for (int cc = 0; cc < 16; ++cc){
        if (cc < 15) stage_load(cc+1);
        const u16* abp = actb[cc & 1];
        #pragma unroll
        for (int dy = 0; dy < 3; ++dy){
            // preload all 12 A-fragments for this dy (3 dx x 4 mf)
            short8 A[3][4];
            #pragma unroll
            for (int dx = 0; dx < 3; ++dx){
                const u16* wdp = wp + (size_t)((dy*3+dx)*16 + cc)*512*40 + abase;
                #pragma unroll
                for (int mf = 0; mf < 4; ++mf)
                    A[dx][mf] = *(const short8*)&wdp[mf*640 + aoff];
            }
            #pragma unroll
            for (int dx = 0; dx < 3; ++dx){
                int shift = (dy*10 + dx)*40;
                #pragma unroll
                for (int nf = 0; nf < 4; ++nf){
                    short8 B = *(const short8*)&abp[bro[nf] + shift];
                    #pragma unroll
                    for (int mf = 0; mf < 4; ++mf)
                        acc[mf][nf] = MFMA(A[dx][mf], B, acc[mf][nf]);
                }
            }
        }
        if (cc < 15) stage_store((cc+1) & 1);
    }

    if (DOWN){
        // fused 1x1 stride-2 downsample from x (NCHW f32), K=256 in 8 chunks
        for (int dc = 0; dc < 8; ++dc){
            #pragma unroll
            for (int it = 0; it < 16; ++it){
                int f = it*64 + lane;                // 1024 dword-pairs
                int cip = f >> 6, px2 = f & 63;
                int ipx = (px2>>3)*32 + (px2&7)*2;
                const float* src = &x[(((size_t)b*256 + dc*32 + 2*cip)*256) + ipx];
                *(u32*)&actb[0][px2*40 + cip*2] = pack2(src[0], src[256]);
            }
            const u16* wdp = wpd + (size_t)(dc*512)*40 + abase;
            short8 A[4];
            #pragma unroll
            for (int mf = 0; mf < 4; ++mf)
                A[mf] = *(const short8*)&wdp[mf*640 + aoff];
            #pragma unroll
            for (int nf = 0; nf < 4; ++nf){
                int rd = nf*16 + ln;
                short8 B = *(const short8*)&actb[0][rd*40 + kg*8];
                #pragma unroll
                for (int mf = 0; mf < 4; ++mf)
                    acc[mf][nf] = MFMA(A[mf], B, acc[mf][nf]);
            }
        }
    }

    #pragma unroll
    for (int mf = 0; mf < 4; ++mf){
        int co0 = cot*64 + mf*16 + kg*4;
        float4 bv = *(const float4*)&bnb[co0];
        if (DOWN){
            float4 dv = *(const float4*)&dbb[co0];
            bv.x += dv.x; bv.y += dv.y; bv.z += dv.z; bv.w += dv.w;
        }
        #pragma unroll
        for (int nf = 0; nf < 4; ++nf){
            int px = nf*16 + ln;
            size_t o = (((size_t)b*64) + px)*512 + co0;
            f32x4 a = acc[mf][nf];
            float v0 = a[0] + bv.x, v1 = a[1] + bv.y;
            float v2 = a[2] + bv.z, v3 = a[3] + bv.w;
            if (RES){
                ushort4 rv = *(const ushort4*)&res[o];
                v0 += b2f(rv.x); v1 += b2f(rv.y); v2 += b2f(rv.z); v3 += b2f(rv.w);
            }
            ushort4 st;
            st.x = f2b(fmaxf(v0, 0.f)); st.y = f2b(fmaxf(v1, 0.f));
            st.z = f2b(fmaxf(v2, 0.f)); st.w = f2b(fmaxf(v3, 0.f));
            *(ushort4*)&out[o] = st;
        }
    }
}

// ---------------------------------------------------------------------------
// head: GAP(8x8) + linear 512->200 (unchanged).
// ---------------------------------------------------------------------------
__global__ __launch_bounds__(256)
void head_kernel(const u16* __restrict__ z, const float* __restrict__ hw,
                 float* __restrict__ pred)
{
    const int b = blockIdx.x, tid = threadIdx.x;
    __shared__ float feat[512];
    float s0 = 0.f, s1 = 0.f;
    for (int px = 0; px < 64; ++px){
        u32 u = *(const u32*)&z[(((size_t)b*64 + px)*512) + 2*tid];
        s0 += b2f((u16)(u & 0xFFFF));
        s1 += b2f((u16)(u >> 16));
    }
    feat[2*tid]   = s0 * (1.f/64.f);
    feat[2*tid+1] = s1 * (1.f/64.f);
    __syncthreads();
    if (tid < 200){
        float acc = 0.f;
        const float4* hp = (const float4*)&hw[(size_t)tid*512];
        #pragma unroll 8
        for (int i = 0; i < 128; ++i){
            float4 h = hp[i];
            float4 f = *(const float4*)&feat[i*4];
            acc += h.x*f.x + h.y*f.y + h.z*f.z + h.w*f.w;
        }
        pred[b*200 + tid] = acc;
    }
}

// ---------------------------------------------------------------------------
// gram: fused embed (emb LDS-resident) + Gram + sigmoid (unchanged).
// ---------------------------------------------------------------------------
__global__ __launch_bounds__(512, 2)
void gram_kernel(const float* __restrict__ x, const u16* __restrict__ wpe,
                 const float* __restrict__ eb, float* __restrict__ vol)
{
    const int b = blockIdx.x, tid = threadIdx.x;
    const int wid = tid >> 6, lane = tid & 63;
    const int ln = lane & 15, kg = lane >> 4;

    __shared__ u16 embl[256*136];        // 69,632 B
    __shared__ u16 xbl[256*40];          // 20,480 B
    __shared__ u16 ewl[128*40];          // 10,240 B

    f32x4 zero4 = {0.f,0.f,0.f,0.f};
    f32x4 ae[8][2];
    #pragma unroll
    for (int mf = 0; mf < 8; ++mf){ ae[mf][0] = zero4; ae[mf][1] = zero4; }

    for (int cc = 0; cc < 8; ++cc){
        __syncthreads();
        #pragma unroll
        for (int it = 0; it < 8; ++it){
            int f = it*512 + tid;
            int cip = f >> 8, px = f & 255;
            const float* src = &x[(((size_t)b*256 + cc*32 + 2*cip)*256) + px];
            *(u32*)&xbl[px*40 + 2*cip] = pack2(src[0], src[256]);
        }
        for (int j = tid; j < 640; j += 512)
            *(short8*)&ewl[j*8] = *(const short8*)&wpe[(cc*128)*40 + j*8];
        __syncthreads();
        short8 A[8];
        #pragma unroll
        for (int mf = 0; mf < 8; ++mf)
            A[mf] = *(const short8*)&ewl[(mf*16 + ln)*40 + kg*8];
        #pragma unroll
        for (int nf = 0; nf < 2; ++nf){
            short8 B = *(const short8*)&xbl[(wid*32 + nf*16 + ln)*40 + kg*8];
            #pragma unroll
            for (int mf = 0; mf < 8; ++mf)
                ae[mf][nf] = MFMA(A[mf], B, ae[mf][nf]);
        }
    }
    #pragma unroll
    for (int mf = 0; mf < 8; ++mf){
        int e0 = mf*16 + kg*4;
        float4 bv = *(const float4*)&eb[e0];
        #pragma unroll
        for (int nf = 0; nf < 2; ++nf){
            int px = wid*32 + nf*16 + ln;
            f32x4 a = ae[mf][nf];
            ushort4 st;
            st.x = f2b(a[0] + bv.x); st.y = f2b(a[1] + bv.y);
            st.z = f2b(a[2] + bv.z); st.w = f2b(a[3] + bv.w);
            *(ushort4*)&embl[px*136 + e0] = st;
        }
    }
    __syncthreads();

    const int wq = wid >> 2, wi = wid & 3;
    f32x4 g[8][4];
    #pragma unroll
    for (int mf = 0; mf < 8; ++mf)
        #pragma unroll
        for (int nf = 0; nf < 4; ++nf) g[mf][nf] = zero4;

    #pragma unroll
    for (int ks = 0; ks < 4; ++ks){
        short8 A[8];
        #pragma unroll
        for (int mf = 0; mf < 8; ++mf)
            A[mf] = *(const short8*)&embl[(wq*128 + mf*16 + ln)*136 + ks*32 + kg*8];
        #pragma unroll
        for (int nf = 0; nf < 4; ++nf){
            short8 B = *(const short8*)&embl[(wi*64 + nf*16 + ln)*136 + ks*32 + kg*8];
            #pragma unroll
            for (int mf = 0; mf < 8; ++mf)
                g[mf][nf] = MFMA(A[mf], B, g[mf][nf]);
        }
    }
    const float sc = 0.08838834764831845f;   // 1/sqrt(128)
    #pragma unroll
    for (int mf = 0; mf < 8; ++mf){
        #pragma unroll
        for (int nf = 0; nf < 4; ++nf){
            int i = wi*64 + nf*16 + ln;
            #pragma unroll
            for (int r = 0; r < 4; ++r){
                int q = wq*128 + mf*16 + kg*4 + r;
                vol[(((size_t)b*256 + q)*256) + i] = sigmoidf_(g[mf][nf][r] * sc);
            }
        }
    }
}

// ---------------------------------------------------------------------------
extern "C" void kernel_launch(void* const* d_in, const int* in_sizes, int n_in,
                              void* d_out, int out_size, void* d_ws, size_t ws_size,
                              hipStream_t stream)
{
    const float* x    = (const float*)d_in[0];
    const float* ew   = (const float*)d_in[1];
    const float* eb   = (const float*)d_in[2];
    const float* w1   = (const float*)d_in[3];
    const float* bn1s = (const float*)d_in[4];
    const float* bn1b = (const float*)d_in[5];
    const float* w2   = (const float*)d_in[6];
    const float* bn2s = (const float*)d_in[7];
    const float* bn2b = (const float*)d_in[8];
    const float* wd   = (const float*)d_in[9];
    const float* bnds = (const float*)d_in[10];
    const float* bndb = (const float*)d_in[11];
    const float* w3   = (const float*)d_in[12];
    const float* bn3s = (const float*)d_in[13];
    const float* bn3b = (const float*)d_in[14];
    const float* w4   = (const float*)d_in[15];
    const float* bn4s = (const float*)d_in[16];
    const float* bn4b = (const float*)d_in[17];
    const float* hw   = (const float*)d_in[18];

    float* pred = (float*)d_out;            // [256,200]
    float* vol  = pred + 51200;             // [256,256,256] f32

    u16* wp2 = (u16*)d_ws;
    u16* wp3 = wp2 + 2949120;
    u16* wp4 = wp3 + 2949120;
    u16* wp1 = wp4 + 2949120;
    u16* wpd = wp1 + 1474560;
    u16* wpe = wpd + 163840;

    u16* y1 = (u16*)vol;
    u16* y  = y1 + 8388608;
    u16* z1 = y  + 8388608;
    u16* z  = z1 + 8388608;

    prep_kernel<<<41120, 256, 0, stream>>>(w1, bn1s, w2, bn2s, w3, bn3s, w4, bn4s,
                                           wd, bnds, ew, wp1, wp2, wp3, wp4, wpd, wpe);
    conv1_kernel<<<dim3(2,128), 512, 0, stream>>>(x, wp1, bn1b, y1);
    conv_s1_kernel<1,0><<<dim3(256,8), 64, 0, stream>>>(y1, wp2, bn2b, x, wpd, bndb,
                                                        nullptr, y);
    conv_s1_kernel<0,0><<<dim3(256,8), 64, 0, stream>>>(y, wp3, bn3b, nullptr, nullptr,
                                                        nullptr, nullptr, z1);
    conv_s1_kernel<0,1><<<dim3(256,8), 64, 0, stream>>>(z1, wp4, bn4b, nullptr, nullptr,
                                                        nullptr, y, z);
    head_kernel<<<256, 256, 0, stream>>>(z, hw, pred);
    gram_kernel<<<256, 512, 0, stream>>>(x, wpe, eb, vol);
}